// Round 2
// baseline (3435.025 us; speedup 1.0000x reference)
//
#include <hip/hip_runtime.h>
#include <stdint.h>

#define N_NODES 100000
#define N_EDGES 1600000
#define N_GRAPHS 128
#define DIN 100
#define DOUT 200

// ---------- init: zero cnt, init graph bounds ----------
__global__ void k_init(int* __restrict__ cnt, int* __restrict__ gstart,
                       int* __restrict__ gend, int n) {
  int i = blockIdx.x * blockDim.x + threadIdx.x;
  if (i < n) cnt[i] = 0;
  if (i < N_GRAPHS) { gstart[i] = 0x7fffffff; gend[i] = -1; }
}

// ---------- degree / dinv ----------
__global__ void k_count(const int* __restrict__ dst, int* __restrict__ cnt, int e) {
  int i = blockIdx.x * blockDim.x + threadIdx.x;
  if (i < e) atomicAdd(&cnt[dst[i]], 1);
}

__global__ void k_dinv(const int* __restrict__ cnt, float* __restrict__ dinv, int n) {
  int i = blockIdx.x * blockDim.x + threadIdx.x;
  if (i < n) dinv[i] = rsqrtf((float)cnt[i] + 1.0f);
}

// ---------- CSR build: scan ----------
__global__ void k_scan1(const int* __restrict__ cnt, int* __restrict__ rowptr,
                        int* __restrict__ bsum, int n) {
  __shared__ int lds[256];
  int t = threadIdx.x, blk = blockIdx.x;
  int base = blk * 1024 + t * 4;
  int v0 = (base + 0 < n) ? cnt[base + 0] : 0;
  int v1 = (base + 1 < n) ? cnt[base + 1] : 0;
  int v2 = (base + 2 < n) ? cnt[base + 2] : 0;
  int v3 = (base + 3 < n) ? cnt[base + 3] : 0;
  int s = v0 + v1 + v2 + v3;
  lds[t] = s;
  __syncthreads();
  for (int off = 1; off < 256; off <<= 1) {
    int x = (t >= off) ? lds[t - off] : 0;
    __syncthreads();
    lds[t] += x;
    __syncthreads();
  }
  int excl = lds[t] - s;
  if (t == 255) bsum[blk] = lds[255];
  int run = excl;
  if (base + 0 < n) { rowptr[base + 0] = run; } run += v0;
  if (base + 1 < n) { rowptr[base + 1] = run; } run += v1;
  if (base + 2 < n) { rowptr[base + 2] = run; } run += v2;
  if (base + 3 < n) { rowptr[base + 3] = run; }
}

__global__ void k_scan2(int* __restrict__ bsum, int nb) {
  __shared__ int lds[128];
  int t = threadIdx.x;
  int v = (t < nb) ? bsum[t] : 0;
  lds[t] = v;
  __syncthreads();
  for (int off = 1; off < 128; off <<= 1) {
    int x = (t >= off) ? lds[t - off] : 0;
    __syncthreads();
    lds[t] += x;
    __syncthreads();
  }
  if (t < nb) bsum[t] = lds[t] - v;  // exclusive
}

__global__ void k_scan3(int* __restrict__ rowptr, int* __restrict__ cursor,
                        const int* __restrict__ bsum, int n, int e) {
  int t = threadIdx.x, blk = blockIdx.x;
  int base = blk * 1024 + t * 4;
  int add = bsum[blk];
  #pragma unroll
  for (int j = 0; j < 4; ++j) {
    int i = base + j;
    if (i < n) {
      int r = rowptr[i] + add;
      rowptr[i] = r;
      cursor[i] = r;
    }
  }
  if (blk == 0 && t == 0) rowptr[n] = e;
}

__global__ void k_fill(const int* __restrict__ src, const int* __restrict__ dst,
                       int* __restrict__ cursor, int* __restrict__ col, int e) {
  int i = blockIdx.x * blockDim.x + threadIdx.x;
  if (i < e) {
    int pos = atomicAdd(&cursor[dst[i]], 1);
    col[pos] = src[i];
  }
}

// ---------- GEMM: C[nrows,200] = A[nrows,K] @ W[K,200] (+bias) ----------
__global__ void k_gemm(const float* __restrict__ A, int K, const float* __restrict__ W,
                       const float* __restrict__ bias, float* __restrict__ C, int nrows) {
  int gid = blockIdx.x * blockDim.x + threadIdx.x;
  if (gid >= nrows * 50) return;
  int r = gid / 50;
  int c4 = (gid % 50) * 4;
  const float* a = A + (size_t)r * K;
  float ax = 0.f, ay = 0.f, az = 0.f, aw = 0.f;
  #pragma unroll 4
  for (int k = 0; k < K; ++k) {
    float av = a[k];
    float4 w = *(const float4*)(W + (size_t)k * DOUT + c4);
    ax += av * w.x;
    ay += av * w.y;
    az += av * w.z;
    aw += av * w.w;
  }
  if (bias) {
    ax += bias[c4 + 0];
    ay += bias[c4 + 1];
    az += bias[c4 + 2];
    aw += bias[c4 + 3];
  }
  float4 o = make_float4(ax, ay, az, aw);
  *(float4*)(C + (size_t)r * DOUT + c4) = o;
}

// ---------- aggregation: out[i,:] = relu?( di*sum_e dinv[s]*T[s,:] + di^2*T[i,:] + b ) ----------
__global__ void k_agg(const float* __restrict__ T, const float* __restrict__ dinv,
                      const int* __restrict__ rowptr, const int* __restrict__ col,
                      const float* __restrict__ bias, float* __restrict__ OUT,
                      int n, int relu) {
  int wave = (blockIdx.x * blockDim.x + threadIdx.x) >> 6;
  int lane = threadIdx.x & 63;
  if (wave >= n) return;
  if (lane >= 50) return;
  int node = wave;
  int c4 = lane * 4;
  float ax = 0.f, ay = 0.f, az = 0.f, aw = 0.f;
  int beg = rowptr[node], end = rowptr[node + 1];
  for (int e = beg; e < end; ++e) {
    int s = col[e];
    float w = dinv[s];
    float4 tv = *(const float4*)(T + (size_t)s * DOUT + c4);
    ax += w * tv.x;
    ay += w * tv.y;
    az += w * tv.z;
    aw += w * tv.w;
  }
  float di = dinv[node];
  float dii = di * di;
  float4 sv = *(const float4*)(T + (size_t)node * DOUT + c4);
  float rx = di * ax + dii * sv.x + bias[c4 + 0];
  float ry = di * ay + dii * sv.y + bias[c4 + 1];
  float rz = di * az + dii * sv.z + bias[c4 + 2];
  float rw = di * aw + dii * sv.w + bias[c4 + 3];
  if (relu) {
    rx = fmaxf(rx, 0.f); ry = fmaxf(ry, 0.f);
    rz = fmaxf(rz, 0.f); rw = fmaxf(rw, 0.f);
  }
  float4 o = make_float4(rx, ry, rz, rw);
  *(float4*)(OUT + (size_t)node * DOUT + c4) = o;
}

// ---------- pooling ----------
__global__ void k_bounds(const int* __restrict__ batch, int* __restrict__ gstart,
                         int* __restrict__ gend, int n) {
  int i = blockIdx.x * blockDim.x + threadIdx.x;
  if (i < n) {
    int g = batch[i];
    atomicMin(&gstart[g], i);
    atomicMax(&gend[g], i);
  }
}

__global__ void k_pool(const float* __restrict__ H, const int* __restrict__ gstart,
                       const int* __restrict__ gend, float* __restrict__ pooled) {
  int g = blockIdx.x;
  int t = threadIdx.x;
  if (t >= DOUT) return;
  int s = gstart[g], e = gend[g];
  float m = -3.4e38f;
  for (int i = s; i <= e; ++i) m = fmaxf(m, H[(size_t)i * DOUT + t]);
  pooled[g * DOUT + t] = m;
}

__global__ void k_cls(const float* __restrict__ pooled, const float* __restrict__ Wcls,
                      const float* __restrict__ bcls, float* __restrict__ out) {
  int g = threadIdx.x;
  if (g >= N_GRAPHS) return;
  float l0 = bcls[0], l1 = bcls[1];
  for (int d = 0; d < DOUT; ++d) {
    float p = pooled[g * DOUT + d];
    l0 += p * Wcls[d * 2 + 0];
    l1 += p * Wcls[d * 2 + 1];
  }
  float m = fmaxf(l0, l1);
  float e0 = expf(l0 - m), e1 = expf(l1 - m);
  float inv = 1.0f / (e0 + e1);
  out[g * 2 + 0] = e0 * inv;
  out[g * 2 + 1] = e1 * inv;
}

static inline size_t align256(size_t x) { return (x + 255) & ~(size_t)255; }

extern "C" void kernel_launch(void* const* d_in, const int* in_sizes, int n_in,
                              void* d_out, int out_size, void* d_ws, size_t ws_size,
                              hipStream_t stream) {
  const float* x     = (const float*)d_in[0];
  const int*   ei    = (const int*)d_in[1];
  const int*   batch = (const int*)d_in[2];
  const float* W1    = (const float*)d_in[3];
  const float* b1    = (const float*)d_in[4];
  const float* Wc    = (const float*)d_in[5];
  const float* bc    = (const float*)d_in[6];
  const float* W2    = (const float*)d_in[7];
  const float* b2    = (const float*)d_in[8];
  const float* W3    = (const float*)d_in[9];
  const float* b3    = (const float*)d_in[10];
  const float* Wcls  = (const float*)d_in[11];
  const float* bcls  = (const float*)d_in[12];
  float* out = (float*)d_out;

  const int N = N_NODES, E = N_EDGES;
  const int* src = ei;
  const int* dst = ei + E;

  char* ws = (char*)d_ws;
  size_t off = 0;
  float* dinv   = (float*)(ws + off); off = align256(off + (size_t)N * 4);
  int*   cnt    = (int*)  (ws + off); off = align256(off + (size_t)N * 4);
  int*   rowptr = (int*)  (ws + off); off = align256(off + (size_t)(N + 1) * 4);
  int*   cursor = (int*)  (ws + off); off = align256(off + (size_t)N * 4);
  int*   col    = (int*)  (ws + off); off = align256(off + (size_t)E * 4);
  int*   bsum   = (int*)  (ws + off); off = align256(off + 1024);
  int*   gstart = (int*)  (ws + off); off = align256(off + 512);
  int*   gend   = (int*)  (ws + off); off = align256(off + 512);
  float* pooled = (float*)(ws + off); off = align256(off + (size_t)N_GRAPHS * DOUT * 4);
  float* bufA   = (float*)(ws + off); off = align256(off + (size_t)N * DOUT * 4);
  float* bufB   = (float*)(ws + off); off = align256(off + (size_t)N * DOUT * 4);

  int eb = (E + 255) / 256;
  int nb = (N + 255) / 256;
  int sb = (N + 1023) / 1024;  // 98

  k_init<<<nb, 256, 0, stream>>>(cnt, gstart, gend, N);
  k_count<<<eb, 256, 0, stream>>>(dst, cnt, E);
  k_dinv<<<nb, 256, 0, stream>>>(cnt, dinv, N);
  k_scan1<<<sb, 256, 0, stream>>>(cnt, rowptr, bsum, N);
  k_scan2<<<1, 128, 0, stream>>>(bsum, sb);
  k_scan3<<<sb, 256, 0, stream>>>(rowptr, cursor, bsum, N, E);
  k_fill<<<eb, 256, 0, stream>>>(src, dst, cursor, col, E);
  k_bounds<<<nb, 256, 0, stream>>>(batch, gstart, gend, N);

  int gemmb = (N * 50 + 255) / 256;
  int aggb = (N + 3) / 4;  // 4 waves per block, 1 node per wave

  // layer 1: t1 = x@W1 ; h1 = relu(agg(t1)+b1)
  k_gemm<<<gemmb, 256, 0, stream>>>(x, DIN, W1, nullptr, bufA, N);
  k_agg<<<aggb, 256, 0, stream>>>(bufA, dinv, rowptr, col, b1, bufB, N, 1);
  // t2 = h1@Wc + bc
  k_gemm<<<gemmb, 256, 0, stream>>>(bufB, DOUT, Wc, bc, bufA, N);
  // layer 2: t3 = t2@W2 ; h2 = relu(agg(t3)+b2)
  k_gemm<<<gemmb, 256, 0, stream>>>(bufA, DOUT, W2, nullptr, bufB, N);
  k_agg<<<aggb, 256, 0, stream>>>(bufB, dinv, rowptr, col, b2, bufA, N, 1);
  // layer 3: t4 = h2@W3 ; h3 = agg(t4)+b3
  k_gemm<<<gemmb, 256, 0, stream>>>(bufA, DOUT, W3, nullptr, bufB, N);
  k_agg<<<aggb, 256, 0, stream>>>(bufB, dinv, rowptr, col, b3, bufA, N, 0);

  k_pool<<<N_GRAPHS, 256, 0, stream>>>(bufA, gstart, gend, pooled);
  k_cls<<<1, 128, 0, stream>>>(pooled, Wcls, bcls, out);
}

// Round 3
// 1778.509 us; speedup vs baseline: 1.9314x; 1.9314x over previous
//
#include <hip/hip_runtime.h>
#include <stdint.h>

#define N_NODES 100000
#define N_EDGES 1600000
#define N_GRAPHS 128
#define DIN 100
#define DOUT 200

// ---------- init: zero cnt, init graph bounds ----------
__global__ void k_init(int* __restrict__ cnt, int* __restrict__ gstart,
                       int* __restrict__ gend, int n) {
  int i = blockIdx.x * blockDim.x + threadIdx.x;
  if (i < n) cnt[i] = 0;
  if (i < N_GRAPHS) { gstart[i] = 0x7fffffff; gend[i] = -1; }
}

// ---------- degree / dinv ----------
__global__ void k_count(const int* __restrict__ dst, int* __restrict__ cnt, int e) {
  int i = blockIdx.x * blockDim.x + threadIdx.x;
  if (i < e) atomicAdd(&cnt[dst[i]], 1);
}

__global__ void k_dinv(const int* __restrict__ cnt, float* __restrict__ dinv, int n) {
  int i = blockIdx.x * blockDim.x + threadIdx.x;
  if (i < n) dinv[i] = rsqrtf((float)cnt[i] + 1.0f);
}

// ---------- CSR build: scan ----------
__global__ void k_scan1(const int* __restrict__ cnt, int* __restrict__ rowptr,
                        int* __restrict__ bsum, int n) {
  __shared__ int lds[256];
  int t = threadIdx.x, blk = blockIdx.x;
  int base = blk * 1024 + t * 4;
  int v0 = (base + 0 < n) ? cnt[base + 0] : 0;
  int v1 = (base + 1 < n) ? cnt[base + 1] : 0;
  int v2 = (base + 2 < n) ? cnt[base + 2] : 0;
  int v3 = (base + 3 < n) ? cnt[base + 3] : 0;
  int s = v0 + v1 + v2 + v3;
  lds[t] = s;
  __syncthreads();
  for (int off = 1; off < 256; off <<= 1) {
    int x = (t >= off) ? lds[t - off] : 0;
    __syncthreads();
    lds[t] += x;
    __syncthreads();
  }
  int excl = lds[t] - s;
  if (t == 255) bsum[blk] = lds[255];
  int run = excl;
  if (base + 0 < n) { rowptr[base + 0] = run; } run += v0;
  if (base + 1 < n) { rowptr[base + 1] = run; } run += v1;
  if (base + 2 < n) { rowptr[base + 2] = run; } run += v2;
  if (base + 3 < n) { rowptr[base + 3] = run; }
}

__global__ void k_scan2(int* __restrict__ bsum, int nb) {
  __shared__ int lds[128];
  int t = threadIdx.x;
  int v = (t < nb) ? bsum[t] : 0;
  lds[t] = v;
  __syncthreads();
  for (int off = 1; off < 128; off <<= 1) {
    int x = (t >= off) ? lds[t - off] : 0;
    __syncthreads();
    lds[t] += x;
    __syncthreads();
  }
  if (t < nb) bsum[t] = lds[t] - v;  // exclusive
}

__global__ void k_scan3(int* __restrict__ rowptr, int* __restrict__ cursor,
                        const int* __restrict__ bsum, int n, int e) {
  int t = threadIdx.x, blk = blockIdx.x;
  int base = blk * 1024 + t * 4;
  int add = bsum[blk];
  #pragma unroll
  for (int j = 0; j < 4; ++j) {
    int i = base + j;
    if (i < n) {
      int r = rowptr[i] + add;
      rowptr[i] = r;
      cursor[i] = r;
    }
  }
  if (blk == 0 && t == 0) rowptr[n] = e;
}

__global__ void k_fill(const int* __restrict__ src, const int* __restrict__ dst,
                       int* __restrict__ cursor, int* __restrict__ col, int e) {
  int i = blockIdx.x * blockDim.x + threadIdx.x;
  if (i < e) {
    int pos = atomicAdd(&cursor[dst[i]], 1);
    col[pos] = src[i];
  }
}

// ---------- weight fold: Wc2 = Wc@W2 (200x200), bc2 = bc@W2 ----------
__global__ void k_comb(const float* __restrict__ Wc, const float* __restrict__ bc,
                       const float* __restrict__ W2, float* __restrict__ Wc2,
                       float* __restrict__ bc2) {
  int gid = blockIdx.x * blockDim.x + threadIdx.x;
  if (gid >= 201 * DOUT) return;
  int r = gid / DOUT, c = gid % DOUT;
  const float* a = (r < DOUT) ? (Wc + (size_t)r * DOUT) : bc;
  float s = 0.f;
  for (int k = 0; k < DOUT; ++k) s += a[k] * W2[(size_t)k * DOUT + c];
  if (r < DOUT) Wc2[(size_t)r * DOUT + c] = s;
  else bc2[c] = s;
}

// ---------- GEMM: C[nrows,200] = A[nrows,K] @ W[K,200] (+bias)(+relu) ----------
// one wave = 8 rows; lanes 0..49 each own 4 consecutive cols; k-step of 4
__global__ void k_gemm8(const float* __restrict__ A, int K, const float* __restrict__ W,
                        const float* __restrict__ bias, float* __restrict__ C,
                        int nrows, int relu) {
  int gid = blockIdx.x * blockDim.x + threadIdx.x;
  int wave = gid >> 6, lane = gid & 63;
  if (lane >= 50) return;
  int r0 = wave * 8;
  if (r0 >= nrows) return;
  int c4 = lane * 4;
  float4 acc[8];
  #pragma unroll
  for (int r = 0; r < 8; ++r) acc[r] = make_float4(0.f, 0.f, 0.f, 0.f);
  const float* a0 = A + (size_t)r0 * K;
  for (int k = 0; k < K; k += 4) {
    float4 w0 = *(const float4*)(W + (size_t)(k + 0) * DOUT + c4);
    float4 w1 = *(const float4*)(W + (size_t)(k + 1) * DOUT + c4);
    float4 w2 = *(const float4*)(W + (size_t)(k + 2) * DOUT + c4);
    float4 w3 = *(const float4*)(W + (size_t)(k + 3) * DOUT + c4);
    #pragma unroll
    for (int r = 0; r < 8; ++r) {
      float4 av = *(const float4*)(a0 + (size_t)r * K + k);
      acc[r].x += av.x * w0.x + av.y * w1.x + av.z * w2.x + av.w * w3.x;
      acc[r].y += av.x * w0.y + av.y * w1.y + av.z * w2.y + av.w * w3.y;
      acc[r].z += av.x * w0.z + av.y * w1.z + av.z * w2.z + av.w * w3.z;
      acc[r].w += av.x * w0.w + av.y * w1.w + av.z * w2.w + av.w * w3.w;
    }
  }
  float4 bv = make_float4(0.f, 0.f, 0.f, 0.f);
  if (bias) bv = *(const float4*)(bias + c4);
  #pragma unroll
  for (int r = 0; r < 8; ++r) {
    float4 o;
    o.x = acc[r].x + bv.x; o.y = acc[r].y + bv.y;
    o.z = acc[r].z + bv.z; o.w = acc[r].w + bv.w;
    if (relu) {
      o.x = fmaxf(o.x, 0.f); o.y = fmaxf(o.y, 0.f);
      o.z = fmaxf(o.z, 0.f); o.w = fmaxf(o.w, 0.f);
    }
    *(float4*)(C + (size_t)(r0 + r) * DOUT + c4) = o;
  }
}

// ---------- aggregation D=200: out[i,:] = relu?( di*sum dinv[s]*T[s,:] + di^2*T[i,:] (+b) ) ----------
__global__ void k_agg200(const float* __restrict__ T, const float* __restrict__ dinv,
                         const int* __restrict__ rowptr, const int* __restrict__ col,
                         const float* __restrict__ bias, float* __restrict__ OUT,
                         int relu) {
  int wave = (blockIdx.x * blockDim.x + threadIdx.x) >> 6;
  int lane = threadIdx.x & 63;
  if (wave >= N_NODES || lane >= 50) return;
  int node = wave;
  int c4 = lane * 4;
  float ax = 0.f, ay = 0.f, az = 0.f, aw = 0.f;
  int beg = rowptr[node], end = rowptr[node + 1];
  int e = beg;
  for (; e + 4 <= end; e += 4) {
    int s0 = col[e + 0], s1 = col[e + 1], s2 = col[e + 2], s3 = col[e + 3];
    float w0 = dinv[s0], w1 = dinv[s1], w2 = dinv[s2], w3 = dinv[s3];
    float4 t0 = *(const float4*)(T + (size_t)s0 * DOUT + c4);
    float4 t1 = *(const float4*)(T + (size_t)s1 * DOUT + c4);
    float4 t2 = *(const float4*)(T + (size_t)s2 * DOUT + c4);
    float4 t3 = *(const float4*)(T + (size_t)s3 * DOUT + c4);
    ax += w0 * t0.x + w1 * t1.x + w2 * t2.x + w3 * t3.x;
    ay += w0 * t0.y + w1 * t1.y + w2 * t2.y + w3 * t3.y;
    az += w0 * t0.z + w1 * t1.z + w2 * t2.z + w3 * t3.z;
    aw += w0 * t0.w + w1 * t1.w + w2 * t2.w + w3 * t3.w;
  }
  for (; e < end; ++e) {
    int s = col[e];
    float w = dinv[s];
    float4 tv = *(const float4*)(T + (size_t)s * DOUT + c4);
    ax += w * tv.x; ay += w * tv.y; az += w * tv.z; aw += w * tv.w;
  }
  float di = dinv[node];
  float dii = di * di;
  float4 sv = *(const float4*)(T + (size_t)node * DOUT + c4);
  float rx = di * ax + dii * sv.x;
  float ry = di * ay + dii * sv.y;
  float rz = di * az + dii * sv.z;
  float rw = di * aw + dii * sv.w;
  if (bias) {
    rx += bias[c4 + 0]; ry += bias[c4 + 1];
    rz += bias[c4 + 2]; rw += bias[c4 + 3];
  }
  if (relu) {
    rx = fmaxf(rx, 0.f); ry = fmaxf(ry, 0.f);
    rz = fmaxf(rz, 0.f); rw = fmaxf(rw, 0.f);
  }
  *(float4*)(OUT + (size_t)node * DOUT + c4) = make_float4(rx, ry, rz, rw);
}

// ---------- aggregation D=100 (for raw x): float2 per lane, no bias/relu ----------
__global__ void k_agg100(const float* __restrict__ T, const float* __restrict__ dinv,
                         const int* __restrict__ rowptr, const int* __restrict__ col,
                         float* __restrict__ OUT) {
  int wave = (blockIdx.x * blockDim.x + threadIdx.x) >> 6;
  int lane = threadIdx.x & 63;
  if (wave >= N_NODES || lane >= 50) return;
  int node = wave;
  int c2 = lane * 2;
  float ax = 0.f, ay = 0.f;
  int beg = rowptr[node], end = rowptr[node + 1];
  int e = beg;
  for (; e + 4 <= end; e += 4) {
    int s0 = col[e + 0], s1 = col[e + 1], s2 = col[e + 2], s3 = col[e + 3];
    float w0 = dinv[s0], w1 = dinv[s1], w2 = dinv[s2], w3 = dinv[s3];
    float2 t0 = *(const float2*)(T + (size_t)s0 * DIN + c2);
    float2 t1 = *(const float2*)(T + (size_t)s1 * DIN + c2);
    float2 t2 = *(const float2*)(T + (size_t)s2 * DIN + c2);
    float2 t3 = *(const float2*)(T + (size_t)s3 * DIN + c2);
    ax += w0 * t0.x + w1 * t1.x + w2 * t2.x + w3 * t3.x;
    ay += w0 * t0.y + w1 * t1.y + w2 * t2.y + w3 * t3.y;
  }
  for (; e < end; ++e) {
    int s = col[e];
    float w = dinv[s];
    float2 tv = *(const float2*)(T + (size_t)s * DIN + c2);
    ax += w * tv.x; ay += w * tv.y;
  }
  float di = dinv[node];
  float dii = di * di;
  float2 sv = *(const float2*)(T + (size_t)node * DIN + c2);
  float2 o;
  o.x = di * ax + dii * sv.x;
  o.y = di * ay + dii * sv.y;
  *(float2*)(OUT + (size_t)node * DIN + c2) = o;
}

// ---------- pooling ----------
__global__ void k_bounds(const int* __restrict__ batch, int* __restrict__ gstart,
                         int* __restrict__ gend, int n) {
  int i = blockIdx.x * blockDim.x + threadIdx.x;
  if (i < n) {
    int g = batch[i];
    atomicMin(&gstart[g], i);
    atomicMax(&gend[g], i);
  }
}

#define POOL_CHUNKS 8
__global__ void k_pool1(const float* __restrict__ H, const int* __restrict__ gstart,
                        const int* __restrict__ gend, float* __restrict__ part) {
  int g = blockIdx.x, c = blockIdx.y, t = threadIdx.x;
  if (t >= DOUT) return;
  int s = gstart[g], e = gend[g];
  float m = -3.4e38f;
  if (e >= s) {
    int len = e - s + 1;
    int cs = s + (int)(((long long)len * c) / POOL_CHUNKS);
    int ce = s + (int)(((long long)len * (c + 1)) / POOL_CHUNKS);
    for (int i = cs; i < ce; ++i) m = fmaxf(m, H[(size_t)i * DOUT + t]);
  }
  part[(size_t)(g * POOL_CHUNKS + c) * DOUT + t] = m;
}

__global__ void k_pool2(const float* __restrict__ part, float* __restrict__ pooled) {
  int g = blockIdx.x, t = threadIdx.x;
  if (t >= DOUT) return;
  float m = -3.4e38f;
  #pragma unroll
  for (int c = 0; c < POOL_CHUNKS; ++c)
    m = fmaxf(m, part[(size_t)(g * POOL_CHUNKS + c) * DOUT + t]);
  pooled[(size_t)g * DOUT + t] = m;
}

__global__ void k_cls(const float* __restrict__ pooled, const float* __restrict__ Wcls,
                      const float* __restrict__ bcls, float* __restrict__ out) {
  int g = threadIdx.x;
  if (g >= N_GRAPHS) return;
  float l0 = bcls[0], l1 = bcls[1];
  for (int d = 0; d < DOUT; ++d) {
    float p = pooled[(size_t)g * DOUT + d];
    l0 += p * Wcls[d * 2 + 0];
    l1 += p * Wcls[d * 2 + 1];
  }
  float m = fmaxf(l0, l1);
  float e0 = expf(l0 - m), e1 = expf(l1 - m);
  float inv = 1.0f / (e0 + e1);
  out[g * 2 + 0] = e0 * inv;
  out[g * 2 + 1] = e1 * inv;
}

static inline size_t align256(size_t x) { return (x + 255) & ~(size_t)255; }

extern "C" void kernel_launch(void* const* d_in, const int* in_sizes, int n_in,
                              void* d_out, int out_size, void* d_ws, size_t ws_size,
                              hipStream_t stream) {
  const float* x     = (const float*)d_in[0];
  const int*   ei    = (const int*)d_in[1];
  const int*   batch = (const int*)d_in[2];
  const float* W1    = (const float*)d_in[3];
  const float* b1    = (const float*)d_in[4];
  const float* Wc    = (const float*)d_in[5];
  const float* bc    = (const float*)d_in[6];
  const float* W2    = (const float*)d_in[7];
  const float* b2    = (const float*)d_in[8];
  const float* W3    = (const float*)d_in[9];
  const float* b3    = (const float*)d_in[10];
  const float* Wcls  = (const float*)d_in[11];
  const float* bcls  = (const float*)d_in[12];
  float* out = (float*)d_out;

  const int N = N_NODES, E = N_EDGES;
  const int* src = ei;
  const int* dst = ei + E;

  char* ws = (char*)d_ws;
  size_t off = 0;
  float* dinv   = (float*)(ws + off); off = align256(off + (size_t)N * 4);
  int*   cnt    = (int*)  (ws + off); off = align256(off + (size_t)N * 4);  // reused as Wc2
  int*   rowptr = (int*)  (ws + off); off = align256(off + (size_t)(N + 1) * 4);
  int*   cursor = (int*)  (ws + off); off = align256(off + (size_t)N * 4);  // reused as bc2
  int*   col    = (int*)  (ws + off); off = align256(off + (size_t)E * 4);
  int*   bsum   = (int*)  (ws + off); off = align256(off + 1024);
  int*   gstart = (int*)  (ws + off); off = align256(off + 512);
  int*   gend   = (int*)  (ws + off); off = align256(off + 512);
  float* pooled = (float*)(ws + off); off = align256(off + (size_t)N_GRAPHS * DOUT * 4);
  float* bufA   = (float*)(ws + off); off = align256(off + (size_t)N * DOUT * 4);
  float* bufB   = (float*)(ws + off); off = align256(off + (size_t)N * DOUT * 4);

  float* Wc2 = (float*)cnt;      // 160 KB, alive only after CSR build
  float* bc2 = (float*)cursor;   // 800 B,  alive only after k_fill
  float* part = bufA;            // pooling partials alias bufA (free at pool time)

  int eb = (E + 255) / 256;
  int nb = (N + 255) / 256;
  int sb = (N + 1023) / 1024;  // 98

  // ---- CSR + degree (once, shared by all 3 convs) ----
  k_init<<<nb, 256, 0, stream>>>(cnt, gstart, gend, N);
  k_count<<<eb, 256, 0, stream>>>(dst, cnt, E);
  k_dinv<<<nb, 256, 0, stream>>>(cnt, dinv, N);
  k_scan1<<<sb, 256, 0, stream>>>(cnt, rowptr, bsum, N);
  k_scan2<<<1, 128, 0, stream>>>(bsum, sb);
  k_scan3<<<sb, 256, 0, stream>>>(rowptr, cursor, bsum, N, E);
  k_fill<<<eb, 256, 0, stream>>>(src, dst, cursor, col, E);
  k_bounds<<<nb, 256, 0, stream>>>(batch, gstart, gend, N);
  // fold Wc@W2 (after CSR build so Wc2/bc2 can alias cnt/cursor)
  k_comb<<<(201 * DOUT + 255) / 256, 256, 0, stream>>>(Wc, bc, W2, Wc2, bc2);

  int gemmb = (N / 8 * 64 + 255) / 256;  // 3125 blocks, 8 rows/wave
  int aggb = (N + 3) / 4;                // 1 node/wave, 4 waves/block

  // layer 1 (agg first in DIN=100, then GEMM with bias+relu):
  k_agg100<<<aggb, 256, 0, stream>>>(x, dinv, rowptr, col, bufA);
  k_gemm8<<<gemmb, 256, 0, stream>>>(bufA, DIN, W1, b1, bufB, N, 1);
  // folded middle linear + conv2 pre-mix: t = h1@(Wc@W2) + bc@W2
  k_gemm8<<<gemmb, 256, 0, stream>>>(bufB, DOUT, Wc2, bc2, bufA, N, 0);
  // conv2 aggregate + b2 + relu
  k_agg200<<<aggb, 256, 0, stream>>>(bufA, dinv, rowptr, col, b2, bufB, 1);
  // conv3: t3 = h2@W3 ; h3 = agg(t3) + b3
  k_gemm8<<<gemmb, 256, 0, stream>>>(bufB, DOUT, W3, nullptr, bufA, N, 0);
  k_agg200<<<aggb, 256, 0, stream>>>(bufA, dinv, rowptr, col, b3, bufB, 0);

  // pool (chunked) + classifier
  dim3 pg(N_GRAPHS, POOL_CHUNKS);
  k_pool1<<<pg, 256, 0, stream>>>(bufB, gstart, gend, part);
  k_pool2<<<N_GRAPHS, 256, 0, stream>>>(part, pooled);
  k_cls<<<1, 128, 0, stream>>>(pooled, Wcls, bcls, out);
}

// Round 4
// 1464.345 us; speedup vs baseline: 2.3458x; 1.2145x over previous
//
#include <hip/hip_runtime.h>
#include <stdint.h>

#define N_NODES 100000
#define N_EDGES 1600000
#define N_GRAPHS 128
#define DIN 100
#define DOUT 200

// ---------- init: zero cnt, init graph bounds ----------
__global__ void k_init(int* __restrict__ cnt, int* __restrict__ gstart,
                       int* __restrict__ gend, int n) {
  int i = blockIdx.x * blockDim.x + threadIdx.x;
  if (i < n) cnt[i] = 0;
  if (i < N_GRAPHS) { gstart[i] = 0x7fffffff; gend[i] = -1; }
}

// ---------- degree / dinv ----------
__global__ void k_count(const int* __restrict__ dst, int* __restrict__ cnt, int e) {
  int i = blockIdx.x * blockDim.x + threadIdx.x;
  if (i < e) atomicAdd(&cnt[dst[i]], 1);
}

__global__ void k_dinv(const int* __restrict__ cnt, float* __restrict__ dinv, int n) {
  int i = blockIdx.x * blockDim.x + threadIdx.x;
  if (i < n) dinv[i] = rsqrtf((float)cnt[i] + 1.0f);
}

// ---------- CSR build: scan ----------
__global__ void k_scan1(const int* __restrict__ cnt, int* __restrict__ rowptr,
                        int* __restrict__ bsum, int n) {
  __shared__ int lds[256];
  int t = threadIdx.x, blk = blockIdx.x;
  int base = blk * 1024 + t * 4;
  int v0 = (base + 0 < n) ? cnt[base + 0] : 0;
  int v1 = (base + 1 < n) ? cnt[base + 1] : 0;
  int v2 = (base + 2 < n) ? cnt[base + 2] : 0;
  int v3 = (base + 3 < n) ? cnt[base + 3] : 0;
  int s = v0 + v1 + v2 + v3;
  lds[t] = s;
  __syncthreads();
  for (int off = 1; off < 256; off <<= 1) {
    int x = (t >= off) ? lds[t - off] : 0;
    __syncthreads();
    lds[t] += x;
    __syncthreads();
  }
  int excl = lds[t] - s;
  if (t == 255) bsum[blk] = lds[255];
  int run = excl;
  if (base + 0 < n) { rowptr[base + 0] = run; } run += v0;
  if (base + 1 < n) { rowptr[base + 1] = run; } run += v1;
  if (base + 2 < n) { rowptr[base + 2] = run; } run += v2;
  if (base + 3 < n) { rowptr[base + 3] = run; }
}

__global__ void k_scan2(int* __restrict__ bsum, int nb) {
  __shared__ int lds[128];
  int t = threadIdx.x;
  int v = (t < nb) ? bsum[t] : 0;
  lds[t] = v;
  __syncthreads();
  for (int off = 1; off < 128; off <<= 1) {
    int x = (t >= off) ? lds[t - off] : 0;
    __syncthreads();
    lds[t] += x;
    __syncthreads();
  }
  if (t < nb) bsum[t] = lds[t] - v;  // exclusive
}

__global__ void k_scan3(int* __restrict__ rowptr, int* __restrict__ cursor,
                        const int* __restrict__ bsum, int n, int e) {
  int t = threadIdx.x, blk = blockIdx.x;
  int base = blk * 1024 + t * 4;
  int add = bsum[blk];
  #pragma unroll
  for (int j = 0; j < 4; ++j) {
    int i = base + j;
    if (i < n) {
      int r = rowptr[i] + add;
      rowptr[i] = r;
      cursor[i] = r;
    }
  }
  if (blk == 0 && t == 0) rowptr[n] = e;
}

__global__ void k_fill(const int* __restrict__ src, const int* __restrict__ dst,
                       int* __restrict__ cursor, int* __restrict__ col, int e) {
  int i = blockIdx.x * blockDim.x + threadIdx.x;
  if (i < e) {
    int pos = atomicAdd(&cursor[dst[i]], 1);
    col[pos] = src[i];
  }
}

// ---------- weight fold: Wc2 = Wc@W2 (200x200), bc2 = bc@W2 ----------
__global__ void k_comb(const float* __restrict__ Wc, const float* __restrict__ bc,
                       const float* __restrict__ W2, float* __restrict__ Wc2,
                       float* __restrict__ bc2) {
  int gid = blockIdx.x * blockDim.x + threadIdx.x;
  if (gid >= 201 * DOUT) return;
  int r = gid / DOUT, c = gid % DOUT;
  const float* a = (r < DOUT) ? (Wc + (size_t)r * DOUT) : bc;
  float s = 0.f;
  for (int k = 0; k < DOUT; ++k) s += a[k] * W2[(size_t)k * DOUT + c];
  if (r < DOUT) Wc2[(size_t)r * DOUT + c] = s;
  else bc2[c] = s;
}

// ---------- GEMM: C[nrows,200] = A[nrows,K] @ W[K,200] (+bias)(+relu) ----------
// one wave = 8 rows; lanes 0..49 each own 4 consecutive cols; k-step of 4
__global__ void k_gemm8(const float* __restrict__ A, int K, const float* __restrict__ W,
                        const float* __restrict__ bias, float* __restrict__ C,
                        int nrows, int relu) {
  int gid = blockIdx.x * blockDim.x + threadIdx.x;
  int wave = gid >> 6, lane = gid & 63;
  if (lane >= 50) return;
  int r0 = wave * 8;
  if (r0 >= nrows) return;
  int c4 = lane * 4;
  float4 acc[8];
  #pragma unroll
  for (int r = 0; r < 8; ++r) acc[r] = make_float4(0.f, 0.f, 0.f, 0.f);
  const float* a0 = A + (size_t)r0 * K;
  for (int k = 0; k < K; k += 4) {
    float4 w0 = *(const float4*)(W + (size_t)(k + 0) * DOUT + c4);
    float4 w1 = *(const float4*)(W + (size_t)(k + 1) * DOUT + c4);
    float4 w2 = *(const float4*)(W + (size_t)(k + 2) * DOUT + c4);
    float4 w3 = *(const float4*)(W + (size_t)(k + 3) * DOUT + c4);
    #pragma unroll
    for (int r = 0; r < 8; ++r) {
      float4 av = *(const float4*)(a0 + (size_t)r * K + k);
      acc[r].x += av.x * w0.x + av.y * w1.x + av.z * w2.x + av.w * w3.x;
      acc[r].y += av.x * w0.y + av.y * w1.y + av.z * w2.y + av.w * w3.y;
      acc[r].z += av.x * w0.z + av.y * w1.z + av.z * w2.z + av.w * w3.z;
      acc[r].w += av.x * w0.w + av.y * w1.w + av.z * w2.w + av.w * w3.w;
    }
  }
  float4 bv = make_float4(0.f, 0.f, 0.f, 0.f);
  if (bias) bv = *(const float4*)(bias + c4);
  #pragma unroll
  for (int r = 0; r < 8; ++r) {
    float4 o;
    o.x = acc[r].x + bv.x; o.y = acc[r].y + bv.y;
    o.z = acc[r].z + bv.z; o.w = acc[r].w + bv.w;
    if (relu) {
      o.x = fmaxf(o.x, 0.f); o.y = fmaxf(o.y, 0.f);
      o.z = fmaxf(o.z, 0.f); o.w = fmaxf(o.w, 0.f);
    }
    *(float4*)(C + (size_t)(r0 + r) * DOUT + c4) = o;
  }
}

// ---------- aggregation D=200: out[i,:] = relu?( di*sum dinv[s]*T[s,:] + di^2*T[i,:] (+b) ) ----------
__global__ void k_agg200(const float* __restrict__ T, const float* __restrict__ dinv,
                         const int* __restrict__ rowptr, const int* __restrict__ col,
                         const float* __restrict__ bias, float* __restrict__ OUT,
                         int relu) {
  int wave = (blockIdx.x * blockDim.x + threadIdx.x) >> 6;
  int lane = threadIdx.x & 63;
  if (wave >= N_NODES || lane >= 50) return;
  int node = wave;
  int c4 = lane * 4;
  float ax = 0.f, ay = 0.f, az = 0.f, aw = 0.f;
  int beg = rowptr[node], end = rowptr[node + 1];
  int e = beg;
  for (; e + 4 <= end; e += 4) {
    int s0 = col[e + 0], s1 = col[e + 1], s2 = col[e + 2], s3 = col[e + 3];
    float w0 = dinv[s0], w1 = dinv[s1], w2 = dinv[s2], w3 = dinv[s3];
    float4 t0 = *(const float4*)(T + (size_t)s0 * DOUT + c4);
    float4 t1 = *(const float4*)(T + (size_t)s1 * DOUT + c4);
    float4 t2 = *(const float4*)(T + (size_t)s2 * DOUT + c4);
    float4 t3 = *(const float4*)(T + (size_t)s3 * DOUT + c4);
    ax += w0 * t0.x + w1 * t1.x + w2 * t2.x + w3 * t3.x;
    ay += w0 * t0.y + w1 * t1.y + w2 * t2.y + w3 * t3.y;
    az += w0 * t0.z + w1 * t1.z + w2 * t2.z + w3 * t3.z;
    aw += w0 * t0.w + w1 * t1.w + w2 * t2.w + w3 * t3.w;
  }
  for (; e < end; ++e) {
    int s = col[e];
    float w = dinv[s];
    float4 tv = *(const float4*)(T + (size_t)s * DOUT + c4);
    ax += w * tv.x; ay += w * tv.y; az += w * tv.z; aw += w * tv.w;
  }
  float di = dinv[node];
  float dii = di * di;
  float4 sv = *(const float4*)(T + (size_t)node * DOUT + c4);
  float rx = di * ax + dii * sv.x;
  float ry = di * ay + dii * sv.y;
  float rz = di * az + dii * sv.z;
  float rw = di * aw + dii * sv.w;
  if (bias) {
    rx += bias[c4 + 0]; ry += bias[c4 + 1];
    rz += bias[c4 + 2]; rw += bias[c4 + 3];
  }
  if (relu) {
    rx = fmaxf(rx, 0.f); ry = fmaxf(ry, 0.f);
    rz = fmaxf(rz, 0.f); rw = fmaxf(rw, 0.f);
  }
  *(float4*)(OUT + (size_t)node * DOUT + c4) = make_float4(rx, ry, rz, rw);
}

// ---------- aggregation D=100 (for raw x): float2 per lane, no bias/relu ----------
__global__ void k_agg100(const float* __restrict__ T, const float* __restrict__ dinv,
                         const int* __restrict__ rowptr, const int* __restrict__ col,
                         float* __restrict__ OUT) {
  int wave = (blockIdx.x * blockDim.x + threadIdx.x) >> 6;
  int lane = threadIdx.x & 63;
  if (wave >= N_NODES || lane >= 50) return;
  int node = wave;
  int c2 = lane * 2;
  float ax = 0.f, ay = 0.f;
  int beg = rowptr[node], end = rowptr[node + 1];
  int e = beg;
  for (; e + 4 <= end; e += 4) {
    int s0 = col[e + 0], s1 = col[e + 1], s2 = col[e + 2], s3 = col[e + 3];
    float w0 = dinv[s0], w1 = dinv[s1], w2 = dinv[s2], w3 = dinv[s3];
    float2 t0 = *(const float2*)(T + (size_t)s0 * DIN + c2);
    float2 t1 = *(const float2*)(T + (size_t)s1 * DIN + c2);
    float2 t2 = *(const float2*)(T + (size_t)s2 * DIN + c2);
    float2 t3 = *(const float2*)(T + (size_t)s3 * DIN + c2);
    ax += w0 * t0.x + w1 * t1.x + w2 * t2.x + w3 * t3.x;
    ay += w0 * t0.y + w1 * t1.y + w2 * t2.y + w3 * t3.y;
  }
  for (; e < end; ++e) {
    int s = col[e];
    float w = dinv[s];
    float2 tv = *(const float2*)(T + (size_t)s * DIN + c2);
    ax += w * tv.x; ay += w * tv.y;
  }
  float di = dinv[node];
  float dii = di * di;
  float2 sv = *(const float2*)(T + (size_t)node * DIN + c2);
  float2 o;
  o.x = di * ax + dii * sv.x;
  o.y = di * ay + dii * sv.y;
  *(float2*)(OUT + (size_t)node * DIN + c2) = o;
}

// ---------- pooling: graph bounds via boundary scan (batch is sorted; NO atomics) ----------
__global__ void k_gbound(const int* __restrict__ batch, int* __restrict__ gstart,
                         int* __restrict__ gend, int n) {
  int i = blockIdx.x * blockDim.x + threadIdx.x;
  if (i >= n) return;
  int g = batch[i];
  if (i == 0 || batch[i - 1] != g) gstart[g] = i;
  if (i == n - 1 || batch[i + 1] != g) gend[g] = i;
}

#define POOL_CHUNKS 8
__global__ void k_pool1(const float* __restrict__ H, const int* __restrict__ gstart,
                        const int* __restrict__ gend, float* __restrict__ part) {
  int g = blockIdx.x, c = blockIdx.y, t = threadIdx.x;
  if (t >= DOUT) return;
  int s = gstart[g], e = gend[g];
  float m = -3.4e38f;
  if (e >= s) {
    int len = e - s + 1;
    int cs = s + (int)(((long long)len * c) / POOL_CHUNKS);
    int ce = s + (int)(((long long)len * (c + 1)) / POOL_CHUNKS);
    for (int i = cs; i < ce; ++i) m = fmaxf(m, H[(size_t)i * DOUT + t]);
  }
  part[(size_t)(g * POOL_CHUNKS + c) * DOUT + t] = m;
}

__global__ void k_pool2(const float* __restrict__ part, float* __restrict__ pooled) {
  int g = blockIdx.x, t = threadIdx.x;
  if (t >= DOUT) return;
  float m = -3.4e38f;
  #pragma unroll
  for (int c = 0; c < POOL_CHUNKS; ++c)
    m = fmaxf(m, part[(size_t)(g * POOL_CHUNKS + c) * DOUT + t]);
  pooled[(size_t)g * DOUT + t] = m;
}

__global__ void k_cls(const float* __restrict__ pooled, const float* __restrict__ Wcls,
                      const float* __restrict__ bcls, float* __restrict__ out) {
  int g = threadIdx.x;
  if (g >= N_GRAPHS) return;
  float l0 = bcls[0], l1 = bcls[1];
  for (int d = 0; d < DOUT; ++d) {
    float p = pooled[(size_t)g * DOUT + d];
    l0 += p * Wcls[d * 2 + 0];
    l1 += p * Wcls[d * 2 + 1];
  }
  float m = fmaxf(l0, l1);
  float e0 = expf(l0 - m), e1 = expf(l1 - m);
  float inv = 1.0f / (e0 + e1);
  out[g * 2 + 0] = e0 * inv;
  out[g * 2 + 1] = e1 * inv;
}

static inline size_t align256(size_t x) { return (x + 255) & ~(size_t)255; }

extern "C" void kernel_launch(void* const* d_in, const int* in_sizes, int n_in,
                              void* d_out, int out_size, void* d_ws, size_t ws_size,
                              hipStream_t stream) {
  const float* x     = (const float*)d_in[0];
  const int*   ei    = (const int*)d_in[1];
  const int*   batch = (const int*)d_in[2];
  const float* W1    = (const float*)d_in[3];
  const float* b1    = (const float*)d_in[4];
  const float* Wc    = (const float*)d_in[5];
  const float* bc    = (const float*)d_in[6];
  const float* W2    = (const float*)d_in[7];
  const float* b2    = (const float*)d_in[8];
  const float* W3    = (const float*)d_in[9];
  const float* b3    = (const float*)d_in[10];
  const float* Wcls  = (const float*)d_in[11];
  const float* bcls  = (const float*)d_in[12];
  float* out = (float*)d_out;

  const int N = N_NODES, E = N_EDGES;
  const int* src = ei;
  const int* dst = ei + E;

  char* ws = (char*)d_ws;
  size_t off = 0;
  float* dinv   = (float*)(ws + off); off = align256(off + (size_t)N * 4);
  int*   cnt    = (int*)  (ws + off); off = align256(off + (size_t)N * 4);  // reused as Wc2
  int*   rowptr = (int*)  (ws + off); off = align256(off + (size_t)(N + 1) * 4);
  int*   cursor = (int*)  (ws + off); off = align256(off + (size_t)N * 4);  // reused as bc2
  int*   col    = (int*)  (ws + off); off = align256(off + (size_t)E * 4);
  int*   bsum   = (int*)  (ws + off); off = align256(off + 1024);
  int*   gstart = (int*)  (ws + off); off = align256(off + 512);
  int*   gend   = (int*)  (ws + off); off = align256(off + 512);
  float* pooled = (float*)(ws + off); off = align256(off + (size_t)N_GRAPHS * DOUT * 4);
  float* bufA   = (float*)(ws + off); off = align256(off + (size_t)N * DOUT * 4);
  float* bufB   = (float*)(ws + off); off = align256(off + (size_t)N * DOUT * 4);

  float* Wc2 = (float*)cnt;      // 160 KB, alive only after CSR build
  float* bc2 = (float*)cursor;   // 800 B,  alive only after k_fill
  float* part = bufA;            // pooling partials alias bufA (free at pool time)

  int eb = (E + 255) / 256;
  int nb = (N + 255) / 256;
  int sb = (N + 1023) / 1024;  // 98

  // ---- CSR + degree (once, shared by all 3 convs) ----
  k_init<<<nb, 256, 0, stream>>>(cnt, gstart, gend, N);
  k_count<<<eb, 256, 0, stream>>>(dst, cnt, E);
  k_dinv<<<nb, 256, 0, stream>>>(cnt, dinv, N);
  k_scan1<<<sb, 256, 0, stream>>>(cnt, rowptr, bsum, N);
  k_scan2<<<1, 128, 0, stream>>>(bsum, sb);
  k_scan3<<<sb, 256, 0, stream>>>(rowptr, cursor, bsum, N, E);
  k_fill<<<eb, 256, 0, stream>>>(src, dst, cursor, col, E);
  // graph bounds: boundary scan on sorted batch (no atomics; was 298us of atomic contention)
  k_gbound<<<nb, 256, 0, stream>>>(batch, gstart, gend, N);
  // fold Wc@W2 (after CSR build so Wc2/bc2 can alias cnt/cursor)
  k_comb<<<(201 * DOUT + 255) / 256, 256, 0, stream>>>(Wc, bc, W2, Wc2, bc2);

  int gemmb = (N / 8 * 64 + 255) / 256;  // 3125 blocks, 8 rows/wave
  int aggb = (N + 3) / 4;                // 1 node/wave, 4 waves/block

  // layer 1 (agg first in DIN=100, then GEMM with bias+relu):
  k_agg100<<<aggb, 256, 0, stream>>>(x, dinv, rowptr, col, bufA);
  k_gemm8<<<gemmb, 256, 0, stream>>>(bufA, DIN, W1, b1, bufB, N, 1);
  // folded middle linear + conv2 pre-mix: t = h1@(Wc@W2) + bc@W2
  k_gemm8<<<gemmb, 256, 0, stream>>>(bufB, DOUT, Wc2, bc2, bufA, N, 0);
  // conv2 aggregate + b2 + relu
  k_agg200<<<aggb, 256, 0, stream>>>(bufA, dinv, rowptr, col, b2, bufB, 1);
  // conv3: t3 = h2@W3 ; h3 = agg(t3) + b3
  k_gemm8<<<gemmb, 256, 0, stream>>>(bufB, DOUT, W3, nullptr, bufA, N, 0);
  k_agg200<<<aggb, 256, 0, stream>>>(bufA, dinv, rowptr, col, b3, bufB, 0);

  // pool (chunked) + classifier
  dim3 pg(N_GRAPHS, POOL_CHUNKS);
  k_pool1<<<pg, 256, 0, stream>>>(bufB, gstart, gend, part);
  k_pool2<<<N_GRAPHS, 256, 0, stream>>>(part, pooled);
  k_cls<<<1, 128, 0, stream>>>(pooled, Wcls, bcls, out);
}

// Round 5
// 839.044 us; speedup vs baseline: 4.0940x; 1.7453x over previous
//
#include <hip/hip_runtime.h>
#include <stdint.h>

#define N_NODES 100000
#define N_EDGES 1600000
#define N_GRAPHS 128
#define DIN 100
#define DOUT 200
#define LDH 224   // padded f16 row stride (multiple of 32 for MFMA K-steps)

typedef unsigned short u16;
typedef unsigned int u32;
typedef _Float16 f16;
typedef f16 half8 __attribute__((ext_vector_type(8)));
typedef f16 half4 __attribute__((ext_vector_type(4)));
typedef f16 half2v __attribute__((ext_vector_type(2)));
typedef float floatx4 __attribute__((ext_vector_type(4)));

__device__ __forceinline__ float h2f(u16 h) {
  f16 x; __builtin_memcpy(&x, &h, 2); return (float)x;
}
__device__ __forceinline__ u16 f2h(float f) {
  f16 x = (f16)f; u16 r; __builtin_memcpy(&r, &x, 2); return r;
}

// ---------- init: zero cnt, init graph bounds ----------
__global__ void k_init(int* __restrict__ cnt, int* __restrict__ gstart,
                       int* __restrict__ gend, int n) {
  int i = blockIdx.x * blockDim.x + threadIdx.x;
  if (i < n) cnt[i] = 0;
  if (i < N_GRAPHS) { gstart[i] = 0x7fffffff; gend[i] = -1; }
}

// ---------- degree / dinv ----------
__global__ void k_count(const int* __restrict__ dst, int* __restrict__ cnt, int e) {
  int i = blockIdx.x * blockDim.x + threadIdx.x;
  if (i < e) atomicAdd(&cnt[dst[i]], 1);
}

__global__ void k_dinv(const int* __restrict__ cnt, float* __restrict__ dinv, int n) {
  int i = blockIdx.x * blockDim.x + threadIdx.x;
  if (i < n) dinv[i] = rsqrtf((float)cnt[i] + 1.0f);
}

// ---------- CSR build: scan ----------
__global__ void k_scan1(const int* __restrict__ cnt, int* __restrict__ rowptr,
                        int* __restrict__ bsum, int n) {
  __shared__ int lds[256];
  int t = threadIdx.x, blk = blockIdx.x;
  int base = blk * 1024 + t * 4;
  int v0 = (base + 0 < n) ? cnt[base + 0] : 0;
  int v1 = (base + 1 < n) ? cnt[base + 1] : 0;
  int v2 = (base + 2 < n) ? cnt[base + 2] : 0;
  int v3 = (base + 3 < n) ? cnt[base + 3] : 0;
  int s = v0 + v1 + v2 + v3;
  lds[t] = s;
  __syncthreads();
  for (int off = 1; off < 256; off <<= 1) {
    int x = (t >= off) ? lds[t - off] : 0;
    __syncthreads();
    lds[t] += x;
    __syncthreads();
  }
  int excl = lds[t] - s;
  if (t == 255) bsum[blk] = lds[255];
  int run = excl;
  if (base + 0 < n) { rowptr[base + 0] = run; } run += v0;
  if (base + 1 < n) { rowptr[base + 1] = run; } run += v1;
  if (base + 2 < n) { rowptr[base + 2] = run; } run += v2;
  if (base + 3 < n) { rowptr[base + 3] = run; }
}

__global__ void k_scan2(int* __restrict__ bsum, int nb) {
  __shared__ int lds[128];
  int t = threadIdx.x;
  int v = (t < nb) ? bsum[t] : 0;
  lds[t] = v;
  __syncthreads();
  for (int off = 1; off < 128; off <<= 1) {
    int x = (t >= off) ? lds[t - off] : 0;
    __syncthreads();
    lds[t] += x;
    __syncthreads();
  }
  if (t < nb) bsum[t] = lds[t] - v;  // exclusive
}

__global__ void k_scan3(int* __restrict__ rowptr, int* __restrict__ cursor,
                        const int* __restrict__ bsum, int n, int e) {
  int t = threadIdx.x, blk = blockIdx.x;
  int base = blk * 1024 + t * 4;
  int add = bsum[blk];
  #pragma unroll
  for (int j = 0; j < 4; ++j) {
    int i = base + j;
    if (i < n) {
      int r = rowptr[i] + add;
      rowptr[i] = r;
      cursor[i] = r;
    }
  }
  if (blk == 0 && t == 0) rowptr[n] = e;
}

__global__ void k_fill(const int* __restrict__ src, const int* __restrict__ dst,
                       int* __restrict__ cursor, int* __restrict__ col, int e) {
  int i = blockIdx.x * blockDim.x + threadIdx.x;
  if (i < e) {
    int pos = atomicAdd(&cursor[dst[i]], 1);
    col[pos] = src[i];
  }
}

// ---------- weight fold: Wc2 = Wc@W2 (200x200), bc2 = bc@W2 ----------
__global__ void k_comb(const float* __restrict__ Wc, const float* __restrict__ bc,
                       const float* __restrict__ W2, float* __restrict__ Wc2,
                       float* __restrict__ bc2) {
  int gid = blockIdx.x * blockDim.x + threadIdx.x;
  if (gid >= 201 * DOUT) return;
  int r = gid / DOUT, c = gid % DOUT;
  const float* a = (r < DOUT) ? (Wc + (size_t)r * DOUT) : bc;
  float s = 0.f;
  for (int k = 0; k < DOUT; ++k) s += a[k] * W2[(size_t)k * DOUT + c];
  if (r < DOUT) Wc2[(size_t)r * DOUT + c] = s;
  else bc2[c] = s;
}

// ---------- weight pre-pack into MFMA B-fragment order ----------
// frag(ks, ct, lane, j) = f16( W[k][n] ), n = ct*16 + (lane&15), k = ks*32 + (lane>>4)*8 + j
__global__ void k_pack(const float* __restrict__ W, int K, int nfrag, u16* __restrict__ out) {
  int idx = blockIdx.x * blockDim.x + threadIdx.x;  // (ks*13+ct)*64 + lane
  if (idx >= nfrag) return;
  int lane = idx & 63;
  int t = idx >> 6;
  int ct = t % 13, ks = t / 13;
  int n = ct * 16 + (lane & 15);
  int kbase = ks * 32 + (lane >> 4) * 8;
  u16 v[8];
  #pragma unroll
  for (int j = 0; j < 8; ++j) {
    int k = kbase + j;
    float f = (k < K && n < DOUT) ? W[(size_t)k * DOUT + n] : 0.f;
    v[j] = f2h(f);
  }
  uint4 o;
  o.x = (u32)v[0] | ((u32)v[1] << 16);
  o.y = (u32)v[2] | ((u32)v[3] << 16);
  o.z = (u32)v[4] | ((u32)v[5] << 16);
  o.w = (u32)v[6] | ((u32)v[7] << 16);
  *(uint4*)(out + (size_t)idx * 8) = o;
}

// ---------- MFMA GEMM: C[nrows,200] (f16) = A[nrows,lda] (f16) @ Wpk (+bias fp32)(+relu) ----------
// block = 4 waves x 16 rows = 64 rows; 13 col-tiles of 16 (208, cols>=200 forced 0)
template <int NKS>
__global__ void k_gemm_mfma(const u16* __restrict__ A, int lda,
                            const u16* __restrict__ Wpk,
                            const float* __restrict__ bias,
                            u16* __restrict__ C, int relu, int nrows) {
  int wv = threadIdx.x >> 6;
  int lane = threadIdx.x & 63;
  int r0 = blockIdx.x * 64 + wv * 16;
  int m = lane & 15, q = lane >> 4;
  int row = r0 + m;
  bool rowok = (row < nrows);

  half8 afr[NKS];
  const u16* arow = A + (size_t)row * lda + q * 8;
  #pragma unroll
  for (int ks = 0; ks < NKS; ++ks) {
    if (rowok) afr[ks] = *(const half8*)(arow + ks * 32);
    else       afr[ks] = half8{0, 0, 0, 0, 0, 0, 0, 0};
  }

  floatx4 acc[13];
  #pragma unroll
  for (int ct = 0; ct < 13; ++ct) acc[ct] = floatx4{0.f, 0.f, 0.f, 0.f};

  const u16* wp = Wpk + (size_t)lane * 8;
  #pragma unroll
  for (int ks = 0; ks < NKS; ++ks) {
    #pragma unroll
    for (int ct = 0; ct < 13; ++ct) {
      half8 b = *(const half8*)(wp + (size_t)(ks * 13 + ct) * 512);
      acc[ct] = __builtin_amdgcn_mfma_f32_16x16x32_f16(afr[ks], b, acc[ct], 0, 0, 0);
    }
  }

  // C/D layout: col = ct*16 + (lane&15), row = r0 + (lane>>4)*4 + reg
  #pragma unroll
  for (int ct = 0; ct < 13; ++ct) {
    int c = ct * 16 + m;
    bool colok = (c < DOUT);
    float bv = (bias && colok) ? bias[c] : 0.f;
    #pragma unroll
    for (int rg = 0; rg < 4; ++rg) {
      int orow = r0 + q * 4 + rg;
      if (orow < nrows) {
        float v = colok ? (acc[ct][rg] + bv) : 0.f;
        if (relu) v = fmaxf(v, 0.f);
        C[(size_t)orow * LDH + c] = f2h(v);
      }
    }
  }
  // zero-pad cols 208..223 (so this buffer can feed the next GEMM's A-frags)
  int rb = blockIdx.x * 64 + (threadIdx.x >> 2);
  int cp = 208 + (threadIdx.x & 3) * 4;
  if (rb < nrows) {
    uint2 z = make_uint2(0u, 0u);
    *(uint2*)(C + (size_t)rb * LDH + cp) = z;
  }
}

// ---------- aggregation D=200 f16: out = relu?( di*sum dinv[s]*T[s] + di^2*T[i] (+b) ) ----------
__global__ void k_agg200h(const u16* __restrict__ T, const float* __restrict__ dinv,
                          const int* __restrict__ rowptr, const int* __restrict__ col,
                          const float* __restrict__ bias, u16* __restrict__ OUT,
                          int relu) {
  int wave = (blockIdx.x * blockDim.x + threadIdx.x) >> 6;
  int lane = threadIdx.x & 63;
  if (wave >= N_NODES) return;
  int node = wave;
  if (lane >= 50) {
    if (lane < 56) {  // zero-pad cols 200..223
      int c = 200 + (lane - 50) * 4;
      *(half4*)(OUT + (size_t)node * LDH + c) = half4{0, 0, 0, 0};
    }
    return;
  }
  int c4 = lane * 4;
  float ax = 0.f, ay = 0.f, az = 0.f, aw = 0.f;
  int beg = rowptr[node], end = rowptr[node + 1];
  int e = beg;
  for (; e + 4 <= end; e += 4) {
    int s0 = col[e + 0], s1 = col[e + 1], s2 = col[e + 2], s3 = col[e + 3];
    float w0 = dinv[s0], w1 = dinv[s1], w2 = dinv[s2], w3 = dinv[s3];
    half4 t0 = *(const half4*)(T + (size_t)s0 * LDH + c4);
    half4 t1 = *(const half4*)(T + (size_t)s1 * LDH + c4);
    half4 t2 = *(const half4*)(T + (size_t)s2 * LDH + c4);
    half4 t3 = *(const half4*)(T + (size_t)s3 * LDH + c4);
    ax += w0 * (float)t0[0] + w1 * (float)t1[0] + w2 * (float)t2[0] + w3 * (float)t3[0];
    ay += w0 * (float)t0[1] + w1 * (float)t1[1] + w2 * (float)t2[1] + w3 * (float)t3[1];
    az += w0 * (float)t0[2] + w1 * (float)t1[2] + w2 * (float)t2[2] + w3 * (float)t3[2];
    aw += w0 * (float)t0[3] + w1 * (float)t1[3] + w2 * (float)t2[3] + w3 * (float)t3[3];
  }
  for (; e < end; ++e) {
    int s = col[e];
    float w = dinv[s];
    half4 tv = *(const half4*)(T + (size_t)s * LDH + c4);
    ax += w * (float)tv[0]; ay += w * (float)tv[1];
    az += w * (float)tv[2]; aw += w * (float)tv[3];
  }
  float di = dinv[node];
  float dii = di * di;
  half4 sv = *(const half4*)(T + (size_t)node * LDH + c4);
  float rx = di * ax + dii * (float)sv[0];
  float ry = di * ay + dii * (float)sv[1];
  float rz = di * az + dii * (float)sv[2];
  float rw = di * aw + dii * (float)sv[3];
  if (bias) {
    rx += bias[c4 + 0]; ry += bias[c4 + 1];
    rz += bias[c4 + 2]; rw += bias[c4 + 3];
  }
  if (relu) {
    rx = fmaxf(rx, 0.f); ry = fmaxf(ry, 0.f);
    rz = fmaxf(rz, 0.f); rw = fmaxf(rw, 0.f);
  }
  half4 o;
  o[0] = (f16)rx; o[1] = (f16)ry; o[2] = (f16)rz; o[3] = (f16)rw;
  *(half4*)(OUT + (size_t)node * LDH + c4) = o;
}

// ---------- aggregation D=100 from fp32 x -> f16 padded to 128 ----------
__global__ void k_agg100h(const float* __restrict__ T, const float* __restrict__ dinv,
                          const int* __restrict__ rowptr, const int* __restrict__ col,
                          u16* __restrict__ OUT) {
  int wave = (blockIdx.x * blockDim.x + threadIdx.x) >> 6;
  int lane = threadIdx.x & 63;
  if (wave >= N_NODES) return;
  int node = wave;
  if (lane >= 50) {  // zero-pad cols 100..127 (14 lanes x 2)
    int c = 100 + (lane - 50) * 2;
    *(half2v*)(OUT + (size_t)node * LDH + c) = half2v{0, 0};
    return;
  }
  int c2 = lane * 2;
  float ax = 0.f, ay = 0.f;
  int beg = rowptr[node], end = rowptr[node + 1];
  int e = beg;
  for (; e + 4 <= end; e += 4) {
    int s0 = col[e + 0], s1 = col[e + 1], s2 = col[e + 2], s3 = col[e + 3];
    float w0 = dinv[s0], w1 = dinv[s1], w2 = dinv[s2], w3 = dinv[s3];
    float2 t0 = *(const float2*)(T + (size_t)s0 * DIN + c2);
    float2 t1 = *(const float2*)(T + (size_t)s1 * DIN + c2);
    float2 t2 = *(const float2*)(T + (size_t)s2 * DIN + c2);
    float2 t3 = *(const float2*)(T + (size_t)s3 * DIN + c2);
    ax += w0 * t0.x + w1 * t1.x + w2 * t2.x + w3 * t3.x;
    ay += w0 * t0.y + w1 * t1.y + w2 * t2.y + w3 * t3.y;
  }
  for (; e < end; ++e) {
    int s = col[e];
    float w = dinv[s];
    float2 tv = *(const float2*)(T + (size_t)s * DIN + c2);
    ax += w * tv.x; ay += w * tv.y;
  }
  float di = dinv[node];
  float dii = di * di;
  float2 sv = *(const float2*)(T + (size_t)node * DIN + c2);
  half2v o;
  o[0] = (f16)(di * ax + dii * sv.x);
  o[1] = (f16)(di * ay + dii * sv.y);
  *(half2v*)(OUT + (size_t)node * LDH + c2) = o;
}

// ---------- pooling: graph bounds via boundary scan (batch sorted; no atomics) ----------
__global__ void k_gbound(const int* __restrict__ batch, int* __restrict__ gstart,
                         int* __restrict__ gend, int n) {
  int i = blockIdx.x * blockDim.x + threadIdx.x;
  if (i >= n) return;
  int g = batch[i];
  if (i == 0 || batch[i - 1] != g) gstart[g] = i;
  if (i == n - 1 || batch[i + 1] != g) gend[g] = i;
}

#define POOL_CHUNKS 8
__global__ void k_pool1h(const u16* __restrict__ H, const int* __restrict__ gstart,
                         const int* __restrict__ gend, float* __restrict__ part) {
  int g = blockIdx.x, c = blockIdx.y, t = threadIdx.x;
  if (t >= DOUT) return;
  int s = gstart[g], e = gend[g];
  float m = -3.4e38f;
  if (e >= s) {
    int len = e - s + 1;
    int cs = s + (int)(((long long)len * c) / POOL_CHUNKS);
    int ce = s + (int)(((long long)len * (c + 1)) / POOL_CHUNKS);
    for (int i = cs; i < ce; ++i) m = fmaxf(m, h2f(H[(size_t)i * LDH + t]));
  }
  part[(size_t)(g * POOL_CHUNKS + c) * DOUT + t] = m;
}

__global__ void k_pool2(const float* __restrict__ part, float* __restrict__ pooled) {
  int g = blockIdx.x, t = threadIdx.x;
  if (t >= DOUT) return;
  float m = -3.4e38f;
  #pragma unroll
  for (int c = 0; c < POOL_CHUNKS; ++c)
    m = fmaxf(m, part[(size_t)(g * POOL_CHUNKS + c) * DOUT + t]);
  pooled[(size_t)g * DOUT + t] = m;
}

__global__ void k_cls(const float* __restrict__ pooled, const float* __restrict__ Wcls,
                      const float* __restrict__ bcls, float* __restrict__ out) {
  int g = threadIdx.x;
  if (g >= N_GRAPHS) return;
  float l0 = bcls[0], l1 = bcls[1];
  for (int d = 0; d < DOUT; ++d) {
    float p = pooled[(size_t)g * DOUT + d];
    l0 += p * Wcls[d * 2 + 0];
    l1 += p * Wcls[d * 2 + 1];
  }
  float m = fmaxf(l0, l1);
  float e0 = expf(l0 - m), e1 = expf(l1 - m);
  float inv = 1.0f / (e0 + e1);
  out[g * 2 + 0] = e0 * inv;
  out[g * 2 + 1] = e1 * inv;
}

static inline size_t align256(size_t x) { return (x + 255) & ~(size_t)255; }

extern "C" void kernel_launch(void* const* d_in, const int* in_sizes, int n_in,
                              void* d_out, int out_size, void* d_ws, size_t ws_size,
                              hipStream_t stream) {
  const float* x     = (const float*)d_in[0];
  const int*   ei    = (const int*)d_in[1];
  const int*   batch = (const int*)d_in[2];
  const float* W1    = (const float*)d_in[3];
  const float* b1    = (const float*)d_in[4];
  const float* Wc    = (const float*)d_in[5];
  const float* bc    = (const float*)d_in[6];
  const float* W2    = (const float*)d_in[7];
  const float* b2    = (const float*)d_in[8];
  const float* W3    = (const float*)d_in[9];
  const float* b3    = (const float*)d_in[10];
  const float* Wcls  = (const float*)d_in[11];
  const float* bcls  = (const float*)d_in[12];
  float* out = (float*)d_out;

  const int N = N_NODES, E = N_EDGES;
  const int* src = ei;
  const int* dst = ei + E;

  char* ws = (char*)d_ws;
  size_t off = 0;
  float* dinv   = (float*)(ws + off); off = align256(off + (size_t)N * 4);
  int*   cnt    = (int*)  (ws + off); off = align256(off + (size_t)N * 4);  // reused as Wc2 fold
  int*   rowptr = (int*)  (ws + off); off = align256(off + (size_t)(N + 1) * 4);
  int*   cursor = (int*)  (ws + off); off = align256(off + (size_t)N * 4);  // reused as bc2
  int*   col    = (int*)  (ws + off); off = align256(off + (size_t)E * 4);
  int*   bsum   = (int*)  (ws + off); off = align256(off + 1024);
  int*   gstart = (int*)  (ws + off); off = align256(off + 512);
  int*   gend   = (int*)  (ws + off); off = align256(off + 512);
  float* pooled = (float*)(ws + off); off = align256(off + (size_t)N_GRAPHS * DOUT * 4);
  u16*   Wpk1   = (u16*)  (ws + off); off = align256(off + (size_t)4 * 13 * 64 * 8 * 2);
  u16*   Wpk2   = (u16*)  (ws + off); off = align256(off + (size_t)7 * 13 * 64 * 8 * 2);
  u16*   Wpk3   = (u16*)  (ws + off); off = align256(off + (size_t)7 * 13 * 64 * 8 * 2);
  u16*   buf0   = (u16*)  (ws + off); off = align256(off + (size_t)N * LDH * 2);
  u16*   buf1   = (u16*)  (ws + off); off = align256(off + (size_t)N * LDH * 2);
  u16*   buf2   = (u16*)  (ws + off); off = align256(off + (size_t)N * LDH * 2);

  float* Wc2  = (float*)cnt;     // 160 KB < 400 KB, alive only after CSR build
  float* bc2  = (float*)cursor;  // 800 B, alive only after k_fill
  float* part = (float*)buf0;    // pooling partials alias buf0 (dead at pool time)

  int eb = (E + 255) / 256;
  int nb = (N + 255) / 256;
  int sb = (N + 1023) / 1024;

  // ---- CSR + degree (once, shared by all 3 convs) ----
  k_init<<<nb, 256, 0, stream>>>(cnt, gstart, gend, N);
  k_count<<<eb, 256, 0, stream>>>(dst, cnt, E);
  k_dinv<<<nb, 256, 0, stream>>>(cnt, dinv, N);
  k_scan1<<<sb, 256, 0, stream>>>(cnt, rowptr, bsum, N);
  k_scan2<<<1, 128, 0, stream>>>(bsum, sb);
  k_scan3<<<sb, 256, 0, stream>>>(rowptr, cursor, bsum, N, E);
  k_fill<<<eb, 256, 0, stream>>>(src, dst, cursor, col, E);
  k_gbound<<<nb, 256, 0, stream>>>(batch, gstart, gend, N);

  // ---- weight fold + f16 fragment pre-pack ----
  k_comb<<<(201 * DOUT + 255) / 256, 256, 0, stream>>>(Wc, bc, W2, Wc2, bc2);
  k_pack<<<(4 * 13 * 64 + 255) / 256, 256, 0, stream>>>(W1,  DIN,  4 * 13 * 64, Wpk1);
  k_pack<<<(7 * 13 * 64 + 255) / 256, 256, 0, stream>>>(Wc2, DOUT, 7 * 13 * 64, Wpk2);
  k_pack<<<(7 * 13 * 64 + 255) / 256, 256, 0, stream>>>(W3,  DOUT, 7 * 13 * 64, Wpk3);

  int gemmb = (N + 63) / 64;   // 1563 blocks, 64 rows each
  int aggb  = (N + 3) / 4;     // 1 node/wave, 4 waves/block

  // layer 1: aggregate x (DIN=100 -> padded 128), then MFMA GEMM W1 (+b1, relu)
  k_agg100h<<<aggb, 256, 0, stream>>>(x, dinv, rowptr, col, buf0);
  k_gemm_mfma<4><<<gemmb, 256, 0, stream>>>(buf0, LDH, Wpk1, b1, buf1, 1, N);
  // folded middle linear + conv2 pre-mix: T2 = H1 @ (Wc@W2) + bc@W2
  k_gemm_mfma<7><<<gemmb, 256, 0, stream>>>(buf1, LDH, Wpk2, bc2, buf2, 0, N);
  // conv2 aggregate + b2 + relu
  k_agg200h<<<aggb, 256, 0, stream>>>(buf2, dinv, rowptr, col, b2, buf0, 1);
  // conv3: T3 = H2 @ W3 ; H3 = agg(T3) + b3
  k_gemm_mfma<7><<<gemmb, 256, 0, stream>>>(buf0, LDH, Wpk3, nullptr, buf1, 0, N);
  k_agg200h<<<aggb, 256, 0, stream>>>(buf1, dinv, rowptr, col, b3, buf2, 0);

  // pool (chunked) + classifier   (part aliases buf0, dead by now)
  dim3 pg(N_GRAPHS, POOL_CHUNKS);
  k_pool1h<<<pg, 256, 0, stream>>>(buf2, gstart, gend, part);
  k_pool2<<<N_GRAPHS, 256, 0, stream>>>(part, pooled);
  k_cls<<<1, 128, 0, stream>>>(pooled, Wcls, bcls, out);
}

// Round 6
// 719.815 us; speedup vs baseline: 4.7721x; 1.1656x over previous
//
#include <hip/hip_runtime.h>
#include <stdint.h>

#define N_NODES 100000
#define N_EDGES 1600000
#define N_GRAPHS 128
#define DIN 100
#define DOUT 200
#define LDH 224   // padded f16 row stride (multiple of 32 for MFMA K-steps)

#define NB 98        // buckets of 1024 nodes (98*1024 >= 100000)
#define BCAP 18432   // per-bucket capacity; E/NB=16327, sigma~127 -> +16 sigma margin
#define EPB 8192     // edges per block in bucketize

typedef unsigned short u16;
typedef unsigned int u32;
typedef _Float16 f16;
typedef f16 half8 __attribute__((ext_vector_type(8)));
typedef f16 half4 __attribute__((ext_vector_type(4)));
typedef f16 half2v __attribute__((ext_vector_type(2)));
typedef float floatx4 __attribute__((ext_vector_type(4)));

__device__ __forceinline__ float h2f(u16 h) {
  f16 x; __builtin_memcpy(&x, &h, 2); return (float)x;
}
__device__ __forceinline__ u16 f2h(float f) {
  f16 x = (f16)f; u16 r; __builtin_memcpy(&r, &x, 2); return r;
}

// ---------- init: zero bucket cursors, init graph bounds ----------
__global__ void k_init0(int* __restrict__ gcur, int* __restrict__ gstart,
                        int* __restrict__ gend) {
  int t = threadIdx.x;
  if (t < NB) gcur[t] = 0;
  if (t < N_GRAPHS) { gstart[t] = 0x7fffffff; gend[t] = -1; }
}

// ---------- phase A: bucketize edges by dst>>10 ----------
__global__ void k_bucket(const int* __restrict__ src, const int* __restrict__ dst,
                         int* __restrict__ gcur, uint2* __restrict__ ebuf, int E) {
  __shared__ int hist[NB];
  __shared__ int base[NB];
  __shared__ int cur[NB];
  int t = threadIdx.x;
  int e0 = blockIdx.x * EPB;
  int e1 = min(e0 + EPB, E);
  if (t < NB) { hist[t] = 0; cur[t] = 0; }
  __syncthreads();
  for (int i = e0 + t; i < e1; i += 256)
    atomicAdd(&hist[dst[i] >> 10], 1);
  __syncthreads();
  if (t < NB) base[t] = atomicAdd(&gcur[t], hist[t]);
  __syncthreads();
  for (int i = e0 + t; i < e1; i += 256) {
    int d = dst[i];
    int b = d >> 10;
    int off = atomicAdd(&cur[b], 1);
    int pos = base[b] + off;
    if (pos < BCAP)
      ebuf[(size_t)b * BCAP + pos] = make_uint2((u32)d, (u32)src[i]);
  }
}

// ---------- phase B: exclusive scan of bucket counts; rowptr[N]=E ----------
__global__ void k_bscan(const int* __restrict__ gcur, int* __restrict__ boffs,
                        int* __restrict__ rowptr) {
  if (threadIdx.x == 0) {
    int run = 0;
    for (int b = 0; b < NB; ++b) { boffs[b] = run; run += gcur[b]; }
    boffs[NB] = run;
    rowptr[N_NODES] = run;  // == E
  }
}

// ---------- phase C: per-bucket count+scan -> rowptr,dinv ; LDS-cursor scatter -> col ----------
__global__ void k_csr(const uint2* __restrict__ ebuf, const int* __restrict__ gcur,
                      const int* __restrict__ boffs, int* __restrict__ rowptr,
                      float* __restrict__ dinv, int* __restrict__ colv) {
  __shared__ int s_cnt[1024];
  __shared__ int s_cur[1024];
  __shared__ int s_scan[256];
  int b = blockIdx.x, t = threadIdx.x;
  int cnt = gcur[b];
  int base = boffs[b];
  int node0 = b << 10;
  int nlim = N_NODES - node0; if (nlim > 1024) nlim = 1024;
  for (int j = t; j < 1024; j += 256) s_cnt[j] = 0;
  __syncthreads();
  const uint2* eb = ebuf + (size_t)b * BCAP;
  for (int i = t; i < cnt; i += 256)
    atomicAdd(&s_cnt[eb[i].x & 1023], 1);
  __syncthreads();
  int v0 = s_cnt[4 * t + 0], v1 = s_cnt[4 * t + 1];
  int v2 = s_cnt[4 * t + 2], v3 = s_cnt[4 * t + 3];
  int s = v0 + v1 + v2 + v3;
  s_scan[t] = s;
  __syncthreads();
  for (int o = 1; o < 256; o <<= 1) {
    int x = (t >= o) ? s_scan[t - o] : 0;
    __syncthreads();
    s_scan[t] += x;
    __syncthreads();
  }
  int run = s_scan[t] - s;
  int vv[4] = {v0, v1, v2, v3};
  #pragma unroll
  for (int j = 0; j < 4; ++j) {
    int jj = 4 * t + j;
    s_cur[jj] = base + run;
    if (jj < nlim) {
      rowptr[node0 + jj] = base + run;
      dinv[node0 + jj] = rsqrtf((float)vv[j] + 1.0f);
    }
    run += vv[j];
  }
  __syncthreads();
  for (int i = t; i < cnt; i += 256) {
    uint2 e = eb[i];
    int pos = atomicAdd(&s_cur[e.x & 1023], 1);
    colv[pos] = (int)e.y;
  }
}

// ---------- weight fold: Wc2 = Wc@W2 (200x200), bc2 = bc@W2 ----------
__global__ void k_comb(const float* __restrict__ Wc, const float* __restrict__ bc,
                       const float* __restrict__ W2, float* __restrict__ Wc2,
                       float* __restrict__ bc2) {
  int gid = blockIdx.x * blockDim.x + threadIdx.x;
  if (gid >= 201 * DOUT) return;
  int r = gid / DOUT, c = gid % DOUT;
  const float* a = (r < DOUT) ? (Wc + (size_t)r * DOUT) : bc;
  float s = 0.f;
  for (int k = 0; k < DOUT; ++k) s += a[k] * W2[(size_t)k * DOUT + c];
  if (r < DOUT) Wc2[(size_t)r * DOUT + c] = s;
  else bc2[c] = s;
}

// ---------- weight pre-pack into MFMA B-fragment order ----------
// frag(ks, ct, lane, j) = f16( W[k][n] ), n = ct*16 + (lane&15), k = ks*32 + (lane>>4)*8 + j
__global__ void k_pack(const float* __restrict__ W, int K, int nfrag, u16* __restrict__ out) {
  int idx = blockIdx.x * blockDim.x + threadIdx.x;
  if (idx >= nfrag) return;
  int lane = idx & 63;
  int t = idx >> 6;
  int ct = t % 13, ks = t / 13;
  int n = ct * 16 + (lane & 15);
  int kbase = ks * 32 + (lane >> 4) * 8;
  u16 v[8];
  #pragma unroll
  for (int j = 0; j < 8; ++j) {
    int k = kbase + j;
    float f = (k < K && n < DOUT) ? W[(size_t)k * DOUT + n] : 0.f;
    v[j] = f2h(f);
  }
  uint4 o;
  o.x = (u32)v[0] | ((u32)v[1] << 16);
  o.y = (u32)v[2] | ((u32)v[3] << 16);
  o.z = (u32)v[4] | ((u32)v[5] << 16);
  o.w = (u32)v[6] | ((u32)v[7] << 16);
  *(uint4*)(out + (size_t)idx * 8) = o;
}

// ---------- MFMA GEMM: C[nrows,200] (f16) = A[nrows,lda] (f16) @ Wpk (+bias fp32)(+relu) ----------
template <int NKS>
__global__ void k_gemm_mfma(const u16* __restrict__ A, int lda,
                            const u16* __restrict__ Wpk,
                            const float* __restrict__ bias,
                            u16* __restrict__ C, int relu, int nrows) {
  int wv = threadIdx.x >> 6;
  int lane = threadIdx.x & 63;
  int r0 = blockIdx.x * 64 + wv * 16;
  int m = lane & 15, q = lane >> 4;
  int row = r0 + m;
  bool rowok = (row < nrows);

  half8 afr[NKS];
  const u16* arow = A + (size_t)row * lda + q * 8;
  #pragma unroll
  for (int ks = 0; ks < NKS; ++ks) {
    if (rowok) afr[ks] = *(const half8*)(arow + ks * 32);
    else       afr[ks] = half8{0, 0, 0, 0, 0, 0, 0, 0};
  }

  floatx4 acc[13];
  #pragma unroll
  for (int ct = 0; ct < 13; ++ct) acc[ct] = floatx4{0.f, 0.f, 0.f, 0.f};

  const u16* wp = Wpk + (size_t)lane * 8;
  #pragma unroll
  for (int ks = 0; ks < NKS; ++ks) {
    #pragma unroll
    for (int ct = 0; ct < 13; ++ct) {
      half8 b = *(const half8*)(wp + (size_t)(ks * 13 + ct) * 512);
      acc[ct] = __builtin_amdgcn_mfma_f32_16x16x32_f16(afr[ks], b, acc[ct], 0, 0, 0);
    }
  }

  #pragma unroll
  for (int ct = 0; ct < 13; ++ct) {
    int c = ct * 16 + m;
    bool colok = (c < DOUT);
    float bv = (bias && colok) ? bias[c] : 0.f;
    #pragma unroll
    for (int rg = 0; rg < 4; ++rg) {
      int orow = r0 + q * 4 + rg;
      if (orow < nrows) {
        float v = colok ? (acc[ct][rg] + bv) : 0.f;
        if (relu) v = fmaxf(v, 0.f);
        C[(size_t)orow * LDH + c] = f2h(v);
      }
    }
  }
  // zero-pad cols 208..223 (so this buffer can feed the next GEMM's A-frags)
  int rb = blockIdx.x * 64 + (threadIdx.x >> 2);
  int cp = 208 + (threadIdx.x & 3) * 4;
  if (rb < nrows) {
    uint2 z = make_uint2(0u, 0u);
    *(uint2*)(C + (size_t)rb * LDH + cp) = z;
  }
}

// ---------- aggregation D=200 f16 ----------
__global__ void k_agg200h(const u16* __restrict__ T, const float* __restrict__ dinv,
                          const int* __restrict__ rowptr, const int* __restrict__ col,
                          const float* __restrict__ bias, u16* __restrict__ OUT,
                          int relu) {
  int wave = (blockIdx.x * blockDim.x + threadIdx.x) >> 6;
  int lane = threadIdx.x & 63;
  if (wave >= N_NODES) return;
  int node = wave;
  if (lane >= 50) {
    if (lane < 56) {
      int c = 200 + (lane - 50) * 4;
      *(half4*)(OUT + (size_t)node * LDH + c) = half4{0, 0, 0, 0};
    }
    return;
  }
  int c4 = lane * 4;
  float ax = 0.f, ay = 0.f, az = 0.f, aw = 0.f;
  int beg = rowptr[node], end = rowptr[node + 1];
  int e = beg;
  for (; e + 4 <= end; e += 4) {
    int s0 = col[e + 0], s1 = col[e + 1], s2 = col[e + 2], s3 = col[e + 3];
    float w0 = dinv[s0], w1 = dinv[s1], w2 = dinv[s2], w3 = dinv[s3];
    half4 t0 = *(const half4*)(T + (size_t)s0 * LDH + c4);
    half4 t1 = *(const half4*)(T + (size_t)s1 * LDH + c4);
    half4 t2 = *(const half4*)(T + (size_t)s2 * LDH + c4);
    half4 t3 = *(const half4*)(T + (size_t)s3 * LDH + c4);
    ax += w0 * (float)t0[0] + w1 * (float)t1[0] + w2 * (float)t2[0] + w3 * (float)t3[0];
    ay += w0 * (float)t0[1] + w1 * (float)t1[1] + w2 * (float)t2[1] + w3 * (float)t3[1];
    az += w0 * (float)t0[2] + w1 * (float)t1[2] + w2 * (float)t2[2] + w3 * (float)t3[2];
    aw += w0 * (float)t0[3] + w1 * (float)t1[3] + w2 * (float)t2[3] + w3 * (float)t3[3];
  }
  for (; e < end; ++e) {
    int s = col[e];
    float w = dinv[s];
    half4 tv = *(const half4*)(T + (size_t)s * LDH + c4);
    ax += w * (float)tv[0]; ay += w * (float)tv[1];
    az += w * (float)tv[2]; aw += w * (float)tv[3];
  }
  float di = dinv[node];
  float dii = di * di;
  half4 sv = *(const half4*)(T + (size_t)node * LDH + c4);
  float rx = di * ax + dii * (float)sv[0];
  float ry = di * ay + dii * (float)sv[1];
  float rz = di * az + dii * (float)sv[2];
  float rw = di * aw + dii * (float)sv[3];
  if (bias) {
    rx += bias[c4 + 0]; ry += bias[c4 + 1];
    rz += bias[c4 + 2]; rw += bias[c4 + 3];
  }
  if (relu) {
    rx = fmaxf(rx, 0.f); ry = fmaxf(ry, 0.f);
    rz = fmaxf(rz, 0.f); rw = fmaxf(rw, 0.f);
  }
  half4 o;
  o[0] = (f16)rx; o[1] = (f16)ry; o[2] = (f16)rz; o[3] = (f16)rw;
  *(half4*)(OUT + (size_t)node * LDH + c4) = o;
}

// ---------- aggregation D=100 from fp32 x -> f16 padded to 128 ----------
__global__ void k_agg100h(const float* __restrict__ T, const float* __restrict__ dinv,
                          const int* __restrict__ rowptr, const int* __restrict__ col,
                          u16* __restrict__ OUT) {
  int wave = (blockIdx.x * blockDim.x + threadIdx.x) >> 6;
  int lane = threadIdx.x & 63;
  if (wave >= N_NODES) return;
  int node = wave;
  if (lane >= 50) {
    int c = 100 + (lane - 50) * 2;
    *(half2v*)(OUT + (size_t)node * LDH + c) = half2v{0, 0};
    return;
  }
  int c2 = lane * 2;
  float ax = 0.f, ay = 0.f;
  int beg = rowptr[node], end = rowptr[node + 1];
  int e = beg;
  for (; e + 4 <= end; e += 4) {
    int s0 = col[e + 0], s1 = col[e + 1], s2 = col[e + 2], s3 = col[e + 3];
    float w0 = dinv[s0], w1 = dinv[s1], w2 = dinv[s2], w3 = dinv[s3];
    float2 t0 = *(const float2*)(T + (size_t)s0 * DIN + c2);
    float2 t1 = *(const float2*)(T + (size_t)s1 * DIN + c2);
    float2 t2 = *(const float2*)(T + (size_t)s2 * DIN + c2);
    float2 t3 = *(const float2*)(T + (size_t)s3 * DIN + c2);
    ax += w0 * t0.x + w1 * t1.x + w2 * t2.x + w3 * t3.x;
    ay += w0 * t0.y + w1 * t1.y + w2 * t2.y + w3 * t3.y;
  }
  for (; e < end; ++e) {
    int s = col[e];
    float w = dinv[s];
    float2 tv = *(const float2*)(T + (size_t)s * DIN + c2);
    ax += w * tv.x; ay += w * tv.y;
  }
  float di = dinv[node];
  float dii = di * di;
  float2 sv = *(const float2*)(T + (size_t)node * DIN + c2);
  half2v o;
  o[0] = (f16)(di * ax + dii * sv.x);
  o[1] = (f16)(di * ay + dii * sv.y);
  *(half2v*)(OUT + (size_t)node * LDH + c2) = o;
}

// ---------- pooling: graph bounds via boundary scan (batch sorted; no atomics) ----------
__global__ void k_gbound(const int* __restrict__ batch, int* __restrict__ gstart,
                         int* __restrict__ gend, int n) {
  int i = blockIdx.x * blockDim.x + threadIdx.x;
  if (i >= n) return;
  int g = batch[i];
  if (i == 0 || batch[i - 1] != g) gstart[g] = i;
  if (i == n - 1 || batch[i + 1] != g) gend[g] = i;
}

#define POOL_CHUNKS 8
__global__ void k_pool1h(const u16* __restrict__ H, const int* __restrict__ gstart,
                         const int* __restrict__ gend, float* __restrict__ part) {
  int g = blockIdx.x, c = blockIdx.y, t = threadIdx.x;
  if (t >= DOUT) return;
  int s = gstart[g], e = gend[g];
  float m = -3.4e38f;
  if (e >= s) {
    int len = e - s + 1;
    int cs = s + (int)(((long long)len * c) / POOL_CHUNKS);
    int ce = s + (int)(((long long)len * (c + 1)) / POOL_CHUNKS);
    for (int i = cs; i < ce; ++i) m = fmaxf(m, h2f(H[(size_t)i * LDH + t]));
  }
  part[(size_t)(g * POOL_CHUNKS + c) * DOUT + t] = m;
}

__global__ void k_pool2(const float* __restrict__ part, float* __restrict__ pooled) {
  int g = blockIdx.x, t = threadIdx.x;
  if (t >= DOUT) return;
  float m = -3.4e38f;
  #pragma unroll
  for (int c = 0; c < POOL_CHUNKS; ++c)
    m = fmaxf(m, part[(size_t)(g * POOL_CHUNKS + c) * DOUT + t]);
  pooled[(size_t)g * DOUT + t] = m;
}

__global__ void k_cls(const float* __restrict__ pooled, const float* __restrict__ Wcls,
                      const float* __restrict__ bcls, float* __restrict__ out) {
  int g = threadIdx.x;
  if (g >= N_GRAPHS) return;
  float l0 = bcls[0], l1 = bcls[1];
  for (int d = 0; d < DOUT; ++d) {
    float p = pooled[(size_t)g * DOUT + d];
    l0 += p * Wcls[d * 2 + 0];
    l1 += p * Wcls[d * 2 + 1];
  }
  float m = fmaxf(l0, l1);
  float e0 = expf(l0 - m), e1 = expf(l1 - m);
  float inv = 1.0f / (e0 + e1);
  out[g * 2 + 0] = e0 * inv;
  out[g * 2 + 1] = e1 * inv;
}

static inline size_t align256(size_t x) { return (x + 255) & ~(size_t)255; }

extern "C" void kernel_launch(void* const* d_in, const int* in_sizes, int n_in,
                              void* d_out, int out_size, void* d_ws, size_t ws_size,
                              hipStream_t stream) {
  const float* x     = (const float*)d_in[0];
  const int*   ei    = (const int*)d_in[1];
  const int*   batch = (const int*)d_in[2];
  const float* W1    = (const float*)d_in[3];
  const float* b1    = (const float*)d_in[4];
  const float* Wc    = (const float*)d_in[5];
  const float* bc    = (const float*)d_in[6];
  const float* W2    = (const float*)d_in[7];
  const float* b2    = (const float*)d_in[8];
  const float* W3    = (const float*)d_in[9];
  const float* b3    = (const float*)d_in[10];
  const float* Wcls  = (const float*)d_in[11];
  const float* bcls  = (const float*)d_in[12];
  float* out = (float*)d_out;

  const int N = N_NODES, E = N_EDGES;
  const int* src = ei;
  const int* dst = ei + E;

  char* ws = (char*)d_ws;
  size_t off = 0;
  float* dinv   = (float*)(ws + off); off = align256(off + (size_t)N * 4);
  int*   rowptr = (int*)  (ws + off); off = align256(off + (size_t)(N + 1) * 4);
  int*   col    = (int*)  (ws + off); off = align256(off + (size_t)E * 4);
  int*   gcur   = (int*)  (ws + off); off = align256(off + (size_t)NB * 4);
  int*   boffs  = (int*)  (ws + off); off = align256(off + (size_t)(NB + 1) * 4);
  int*   gstart = (int*)  (ws + off); off = align256(off + 512);
  int*   gend   = (int*)  (ws + off); off = align256(off + 512);
  float* pooled = (float*)(ws + off); off = align256(off + (size_t)N_GRAPHS * DOUT * 4);
  float* Wc2    = (float*)(ws + off); off = align256(off + (size_t)DOUT * DOUT * 4);
  float* bc2    = (float*)(ws + off); off = align256(off + (size_t)DOUT * 4);
  u16*   Wpk1   = (u16*)  (ws + off); off = align256(off + (size_t)4 * 13 * 64 * 8 * 2);
  u16*   Wpk2   = (u16*)  (ws + off); off = align256(off + (size_t)7 * 13 * 64 * 8 * 2);
  u16*   Wpk3   = (u16*)  (ws + off); off = align256(off + (size_t)7 * 13 * 64 * 8 * 2);
  u16*   buf0   = (u16*)  (ws + off); off = align256(off + (size_t)N * LDH * 2);
  u16*   buf1   = (u16*)  (ws + off); off = align256(off + (size_t)N * LDH * 2);
  u16*   buf2   = (u16*)  (ws + off); off = align256(off + (size_t)N * LDH * 2);

  uint2* ebuf = (uint2*)buf1;    // 14.5 MB bucket scratch aliases buf1 (dead until GEMM1)
  float* part = (float*)buf0;    // pooling partials alias buf0 (dead at pool time)

  int nb = (N + 255) / 256;

  // ---- CSR + degree via bucketed two-phase build (no fine-grained global atomics) ----
  k_init0<<<1, 128, 0, stream>>>(gcur, gstart, gend);
  k_bucket<<<(E + EPB - 1) / EPB, 256, 0, stream>>>(src, dst, gcur, ebuf, E);
  k_bscan<<<1, 64, 0, stream>>>(gcur, boffs, rowptr);
  k_csr<<<NB, 256, 0, stream>>>(ebuf, gcur, boffs, rowptr, dinv, col);
  k_gbound<<<nb, 256, 0, stream>>>(batch, gstart, gend, N);

  // ---- weight fold + f16 fragment pre-pack ----
  k_comb<<<(201 * DOUT + 255) / 256, 256, 0, stream>>>(Wc, bc, W2, Wc2, bc2);
  k_pack<<<(4 * 13 * 64 + 255) / 256, 256, 0, stream>>>(W1,  DIN,  4 * 13 * 64, Wpk1);
  k_pack<<<(7 * 13 * 64 + 255) / 256, 256, 0, stream>>>(Wc2, DOUT, 7 * 13 * 64, Wpk2);
  k_pack<<<(7 * 13 * 64 + 255) / 256, 256, 0, stream>>>(W3,  DOUT, 7 * 13 * 64, Wpk3);

  int gemmb = (N + 63) / 64;
  int aggb  = (N + 3) / 4;

  // layer 1: aggregate x (DIN=100 -> padded 128), then MFMA GEMM W1 (+b1, relu)
  k_agg100h<<<aggb, 256, 0, stream>>>(x, dinv, rowptr, col, buf0);
  k_gemm_mfma<4><<<gemmb, 256, 0, stream>>>(buf0, LDH, Wpk1, b1, buf1, 1, N);
  // folded middle linear + conv2 pre-mix: T2 = H1 @ (Wc@W2) + bc@W2
  k_gemm_mfma<7><<<gemmb, 256, 0, stream>>>(buf1, LDH, Wpk2, bc2, buf2, 0, N);
  // conv2 aggregate + b2 + relu
  k_agg200h<<<aggb, 256, 0, stream>>>(buf2, dinv, rowptr, col, b2, buf0, 1);
  // conv3: T3 = H2 @ W3 ; H3 = agg(T3) + b3
  k_gemm_mfma<7><<<gemmb, 256, 0, stream>>>(buf0, LDH, Wpk3, nullptr, buf1, 0, N);
  k_agg200h<<<aggb, 256, 0, stream>>>(buf1, dinv, rowptr, col, b3, buf2, 0);

  // pool (chunked) + classifier
  dim3 pg(N_GRAPHS, POOL_CHUNKS);
  k_pool1h<<<pg, 256, 0, stream>>>(buf2, gstart, gend, part);
  k_pool2<<<N_GRAPHS, 256, 0, stream>>>(part, pooled);
  k_cls<<<1, 128, 0, stream>>>(pooled, Wcls, bcls, out);
}

// Round 7
// 704.875 us; speedup vs baseline: 4.8732x; 1.0212x over previous
//
#include <hip/hip_runtime.h>
#include <stdint.h>

#define N_NODES 100000
#define N_EDGES 1600000
#define N_GRAPHS 128
#define DIN 100
#define DOUT 200
#define LDH 224   // padded f16 row stride (multiple of 32 for MFMA K-steps)
#define LDX 128   // padded f16 row stride for the 100-dim input layer

#define NB 98        // buckets of 1024 nodes (98*1024 >= 100000)
#define BCAP 18432   // per-bucket capacity; E/NB=16327, sigma~127 -> +16 sigma margin
#define EPB 8192     // edges per block in bucketize

typedef unsigned short u16;
typedef unsigned int u32;
typedef _Float16 f16;
typedef f16 half8 __attribute__((ext_vector_type(8)));
typedef f16 half4 __attribute__((ext_vector_type(4)));
typedef f16 half2v __attribute__((ext_vector_type(2)));
typedef float floatx4 __attribute__((ext_vector_type(4)));

__device__ __forceinline__ float h2f(u16 h) {
  f16 x; __builtin_memcpy(&x, &h, 2); return (float)x;
}
__device__ __forceinline__ u16 f2h(float f) {
  f16 x = (f16)f; u16 r; __builtin_memcpy(&r, &x, 2); return r;
}
__device__ __forceinline__ float u2f(u32 u) {
  float f; __builtin_memcpy(&f, &u, 4); return f;
}

// ---------- init: zero bucket cursors, init graph bounds ----------
__global__ void k_init0(int* __restrict__ gcur, int* __restrict__ gstart,
                        int* __restrict__ gend) {
  int t = threadIdx.x;
  if (t < NB) gcur[t] = 0;
  if (t < N_GRAPHS) { gstart[t] = 0x7fffffff; gend[t] = -1; }
}

// ---------- phase A: bucketize edges by dst>>10 ----------
__global__ void k_bucket(const int* __restrict__ src, const int* __restrict__ dst,
                         int* __restrict__ gcur, uint2* __restrict__ ebuf, int E) {
  __shared__ int hist[NB];
  __shared__ int base[NB];
  __shared__ int cur[NB];
  int t = threadIdx.x;
  int e0 = blockIdx.x * EPB;
  int e1 = min(e0 + EPB, E);
  if (t < NB) { hist[t] = 0; cur[t] = 0; }
  __syncthreads();
  for (int i = e0 + t; i < e1; i += 256)
    atomicAdd(&hist[dst[i] >> 10], 1);
  __syncthreads();
  if (t < NB) base[t] = atomicAdd(&gcur[t], hist[t]);
  __syncthreads();
  for (int i = e0 + t; i < e1; i += 256) {
    int d = dst[i];
    int b = d >> 10;
    int off = atomicAdd(&cur[b], 1);
    int pos = base[b] + off;
    if (pos < BCAP)
      ebuf[(size_t)b * BCAP + pos] = make_uint2((u32)d, (u32)src[i]);
  }
}

// ---------- phase B: exclusive scan of bucket counts; rowptr[N]=E ----------
__global__ void k_bscan(const int* __restrict__ gcur, int* __restrict__ boffs,
                        int* __restrict__ rowptr) {
  if (threadIdx.x == 0) {
    int run = 0;
    for (int b = 0; b < NB; ++b) { boffs[b] = run; run += gcur[b]; }
    boffs[NB] = run;
    rowptr[N_NODES] = run;  // == E
  }
}

// ---------- phase C: per-bucket count+scan -> rowptr,dinv ; LDS-cursor scatter -> col ----------
__global__ void k_csr(const uint2* __restrict__ ebuf, const int* __restrict__ gcur,
                      const int* __restrict__ boffs, int* __restrict__ rowptr,
                      float* __restrict__ dinv, int* __restrict__ colv) {
  __shared__ int s_cnt[1024];
  __shared__ int s_cur[1024];
  __shared__ int s_scan[256];
  int b = blockIdx.x, t = threadIdx.x;
  int cnt = gcur[b];
  int base = boffs[b];
  int node0 = b << 10;
  int nlim = N_NODES - node0; if (nlim > 1024) nlim = 1024;
  for (int j = t; j < 1024; j += 256) s_cnt[j] = 0;
  __syncthreads();
  const uint2* eb = ebuf + (size_t)b * BCAP;
  for (int i = t; i < cnt; i += 256)
    atomicAdd(&s_cnt[eb[i].x & 1023], 1);
  __syncthreads();
  int v0 = s_cnt[4 * t + 0], v1 = s_cnt[4 * t + 1];
  int v2 = s_cnt[4 * t + 2], v3 = s_cnt[4 * t + 3];
  int s = v0 + v1 + v2 + v3;
  s_scan[t] = s;
  __syncthreads();
  for (int o = 1; o < 256; o <<= 1) {
    int x = (t >= o) ? s_scan[t - o] : 0;
    __syncthreads();
    s_scan[t] += x;
    __syncthreads();
  }
  int run = s_scan[t] - s;
  int vv[4] = {v0, v1, v2, v3};
  #pragma unroll
  for (int j = 0; j < 4; ++j) {
    int jj = 4 * t + j;
    s_cur[jj] = base + run;
    if (jj < nlim) {
      rowptr[node0 + jj] = base + run;
      dinv[node0 + jj] = rsqrtf((float)vv[j] + 1.0f);
    }
    run += vv[j];
  }
  __syncthreads();
  for (int i = t; i < cnt; i += 256) {
    uint2 e = eb[i];
    int pos = atomicAdd(&s_cur[e.x & 1023], 1);
    colv[pos] = (int)e.y;
  }
}

// ---------- fuse dinv into edge list: colw[e] = (src, dinv[src]) ----------
__global__ void k_fusew(const int* __restrict__ col, const float* __restrict__ dinv,
                        uint2* __restrict__ colw, int E) {
  int i = blockIdx.x * blockDim.x + threadIdx.x;
  if (i < E) {
    int s = col[i];
    float w = dinv[s];
    u32 wu; __builtin_memcpy(&wu, &w, 4);
    colw[i] = make_uint2((u32)s, wu);
  }
}

// ---------- x fp32 -> f16 at LDX stride (cols 100..127 zeroed) ----------
__global__ void k_x2h(const float* __restrict__ x, u16* __restrict__ xh) {
  int gid = blockIdx.x * blockDim.x + threadIdx.x;
  int node = gid >> 6, lane = gid & 63;
  if (node >= N_NODES) return;
  if (lane >= 50) {
    int c = 100 + (lane - 50) * 2;
    *(half2v*)(xh + (size_t)node * LDX + c) = half2v{0, 0};
    return;
  }
  float2 v = *(const float2*)(x + (size_t)node * DIN + lane * 2);
  half2v o; o[0] = (f16)v.x; o[1] = (f16)v.y;
  *(half2v*)(xh + (size_t)node * LDX + lane * 2) = o;
}

// ---------- weight fold: Wc2 = Wc@W2 (200x200), bc2 = bc@W2 ----------
__global__ void k_comb(const float* __restrict__ Wc, const float* __restrict__ bc,
                       const float* __restrict__ W2, float* __restrict__ Wc2,
                       float* __restrict__ bc2) {
  int gid = blockIdx.x * blockDim.x + threadIdx.x;
  if (gid >= 201 * DOUT) return;
  int r = gid / DOUT, c = gid % DOUT;
  const float* a = (r < DOUT) ? (Wc + (size_t)r * DOUT) : bc;
  float s = 0.f;
  for (int k = 0; k < DOUT; ++k) s += a[k] * W2[(size_t)k * DOUT + c];
  if (r < DOUT) Wc2[(size_t)r * DOUT + c] = s;
  else bc2[c] = s;
}

// ---------- weight pre-pack into MFMA B-fragment order ----------
// frag(ks, ct, lane, j) = f16( W[k][n] ), n = ct*16 + (lane&15), k = ks*32 + (lane>>4)*8 + j
__global__ void k_pack(const float* __restrict__ W, int K, int nfrag, u16* __restrict__ out) {
  int idx = blockIdx.x * blockDim.x + threadIdx.x;
  if (idx >= nfrag) return;
  int lane = idx & 63;
  int t = idx >> 6;
  int ct = t % 13, ks = t / 13;
  int n = ct * 16 + (lane & 15);
  int kbase = ks * 32 + (lane >> 4) * 8;
  u16 v[8];
  #pragma unroll
  for (int j = 0; j < 8; ++j) {
    int k = kbase + j;
    float f = (k < K && n < DOUT) ? W[(size_t)k * DOUT + n] : 0.f;
    v[j] = f2h(f);
  }
  uint4 o;
  o.x = (u32)v[0] | ((u32)v[1] << 16);
  o.y = (u32)v[2] | ((u32)v[3] << 16);
  o.z = (u32)v[4] | ((u32)v[5] << 16);
  o.w = (u32)v[6] | ((u32)v[7] << 16);
  *(uint4*)(out + (size_t)idx * 8) = o;
}

// ---------- MFMA GEMM: C[nrows,200] (f16) = A[nrows,lda] (f16) @ Wpk (+bias fp32)(+relu) ----------
template <int NKS>
__global__ void k_gemm_mfma(const u16* __restrict__ A, int lda,
                            const u16* __restrict__ Wpk,
                            const float* __restrict__ bias,
                            u16* __restrict__ C, int relu, int nrows) {
  int wv = threadIdx.x >> 6;
  int lane = threadIdx.x & 63;
  int r0 = blockIdx.x * 64 + wv * 16;
  int m = lane & 15, q = lane >> 4;
  int row = r0 + m;
  bool rowok = (row < nrows);

  half8 afr[NKS];
  const u16* arow = A + (size_t)row * lda + q * 8;
  #pragma unroll
  for (int ks = 0; ks < NKS; ++ks) {
    if (rowok) afr[ks] = *(const half8*)(arow + ks * 32);
    else       afr[ks] = half8{0, 0, 0, 0, 0, 0, 0, 0};
  }

  floatx4 acc[13];
  #pragma unroll
  for (int ct = 0; ct < 13; ++ct) acc[ct] = floatx4{0.f, 0.f, 0.f, 0.f};

  const u16* wp = Wpk + (size_t)lane * 8;
  #pragma unroll
  for (int ks = 0; ks < NKS; ++ks) {
    #pragma unroll
    for (int ct = 0; ct < 13; ++ct) {
      half8 b = *(const half8*)(wp + (size_t)(ks * 13 + ct) * 512);
      acc[ct] = __builtin_amdgcn_mfma_f32_16x16x32_f16(afr[ks], b, acc[ct], 0, 0, 0);
    }
  }

  #pragma unroll
  for (int ct = 0; ct < 13; ++ct) {
    int c = ct * 16 + m;
    bool colok = (c < DOUT);
    float bv = (bias && colok) ? bias[c] : 0.f;
    #pragma unroll
    for (int rg = 0; rg < 4; ++rg) {
      int orow = r0 + q * 4 + rg;
      if (orow < nrows) {
        float v = colok ? (acc[ct][rg] + bv) : 0.f;
        if (relu) v = fmaxf(v, 0.f);
        C[(size_t)orow * LDH + c] = f2h(v);
      }
    }
  }
  // zero-pad cols 208..223 (so this buffer can feed the next GEMM's A-frags)
  int rb = blockIdx.x * 64 + (threadIdx.x >> 2);
  int cp = 208 + (threadIdx.x & 3) * 4;
  if (rb < nrows) {
    uint2 z = make_uint2(0u, 0u);
    *(uint2*)(C + (size_t)rb * LDH + cp) = z;
  }
}

// ---------- aggregation D=200 f16, fused (src,dinv) edges, unroll 8 ----------
__global__ void k_agg200h(const u16* __restrict__ T, const float* __restrict__ dinv,
                          const int* __restrict__ rowptr, const uint2* __restrict__ colw,
                          const float* __restrict__ bias, u16* __restrict__ OUT,
                          int relu) {
  int wave = (blockIdx.x * blockDim.x + threadIdx.x) >> 6;
  int lane = threadIdx.x & 63;
  if (wave >= N_NODES) return;
  int node = wave;
  if (lane >= 50) {
    if (lane < 56) {
      int c = 200 + (lane - 50) * 4;
      *(half4*)(OUT + (size_t)node * LDH + c) = half4{0, 0, 0, 0};
    }
    return;
  }
  int c4 = lane * 4;
  float ax = 0.f, ay = 0.f, az = 0.f, aw = 0.f;
  int beg = rowptr[node], end = rowptr[node + 1];
  int e = beg;
  for (; e + 8 <= end; e += 8) {
    uint2 cw[8];
    half4 tv[8];
    #pragma unroll
    for (int j = 0; j < 8; ++j) cw[j] = colw[e + j];
    #pragma unroll
    for (int j = 0; j < 8; ++j)
      tv[j] = *(const half4*)(T + (size_t)cw[j].x * LDH + c4);
    #pragma unroll
    for (int j = 0; j < 8; ++j) {
      float w = u2f(cw[j].y);
      ax += w * (float)tv[j][0];
      ay += w * (float)tv[j][1];
      az += w * (float)tv[j][2];
      aw += w * (float)tv[j][3];
    }
  }
  for (; e < end; ++e) {
    uint2 cw = colw[e];
    float w = u2f(cw.y);
    half4 tv = *(const half4*)(T + (size_t)cw.x * LDH + c4);
    ax += w * (float)tv[0]; ay += w * (float)tv[1];
    az += w * (float)tv[2]; aw += w * (float)tv[3];
  }
  float di = dinv[node];
  float dii = di * di;
  half4 sv = *(const half4*)(T + (size_t)node * LDH + c4);
  float rx = di * ax + dii * (float)sv[0];
  float ry = di * ay + dii * (float)sv[1];
  float rz = di * az + dii * (float)sv[2];
  float rw = di * aw + dii * (float)sv[3];
  if (bias) {
    rx += bias[c4 + 0]; ry += bias[c4 + 1];
    rz += bias[c4 + 2]; rw += bias[c4 + 3];
  }
  if (relu) {
    rx = fmaxf(rx, 0.f); ry = fmaxf(ry, 0.f);
    rz = fmaxf(rz, 0.f); rw = fmaxf(rw, 0.f);
  }
  half4 o;
  o[0] = (f16)rx; o[1] = (f16)ry; o[2] = (f16)rz; o[3] = (f16)rw;
  *(half4*)(OUT + (size_t)node * LDH + c4) = o;
}

// ---------- aggregation D=100 from f16 xh (LDX stride) -> f16 LDX-out, unroll 8 ----------
__global__ void k_agg100h(const u16* __restrict__ T, const float* __restrict__ dinv,
                          const int* __restrict__ rowptr, const uint2* __restrict__ colw,
                          u16* __restrict__ OUT) {
  int wave = (blockIdx.x * blockDim.x + threadIdx.x) >> 6;
  int lane = threadIdx.x & 63;
  if (wave >= N_NODES) return;
  int node = wave;
  if (lane >= 50) {
    int c = 100 + (lane - 50) * 2;
    *(half2v*)(OUT + (size_t)node * LDX + c) = half2v{0, 0};
    return;
  }
  int c2 = lane * 2;
  float ax = 0.f, ay = 0.f;
  int beg = rowptr[node], end = rowptr[node + 1];
  int e = beg;
  for (; e + 8 <= end; e += 8) {
    uint2 cw[8];
    half2v tv[8];
    #pragma unroll
    for (int j = 0; j < 8; ++j) cw[j] = colw[e + j];
    #pragma unroll
    for (int j = 0; j < 8; ++j)
      tv[j] = *(const half2v*)(T + (size_t)cw[j].x * LDX + c2);
    #pragma unroll
    for (int j = 0; j < 8; ++j) {
      float w = u2f(cw[j].y);
      ax += w * (float)tv[j][0];
      ay += w * (float)tv[j][1];
    }
  }
  for (; e < end; ++e) {
    uint2 cw = colw[e];
    float w = u2f(cw.y);
    half2v tv = *(const half2v*)(T + (size_t)cw.x * LDX + c2);
    ax += w * (float)tv[0]; ay += w * (float)tv[1];
  }
  float di = dinv[node];
  float dii = di * di;
  half2v sv = *(const half2v*)(T + (size_t)node * LDX + c2);
  half2v o;
  o[0] = (f16)(di * ax + dii * (float)sv[0]);
  o[1] = (f16)(di * ay + dii * (float)sv[1]);
  *(half2v*)(OUT + (size_t)node * LDX + c2) = o;
}

// ---------- pooling: graph bounds via boundary scan (batch sorted; no atomics) ----------
__global__ void k_gbound(const int* __restrict__ batch, int* __restrict__ gstart,
                         int* __restrict__ gend, int n) {
  int i = blockIdx.x * blockDim.x + threadIdx.x;
  if (i >= n) return;
  int g = batch[i];
  if (i == 0 || batch[i - 1] != g) gstart[g] = i;
  if (i == n - 1 || batch[i + 1] != g) gend[g] = i;
}

#define POOL_CHUNKS 8
__global__ void k_pool1h(const u16* __restrict__ H, const int* __restrict__ gstart,
                         const int* __restrict__ gend, float* __restrict__ part) {
  int g = blockIdx.x, c = blockIdx.y, t = threadIdx.x;
  if (t >= DOUT) return;
  int s = gstart[g], e = gend[g];
  float m = -3.4e38f;
  if (e >= s) {
    int len = e - s + 1;
    int cs = s + (int)(((long long)len * c) / POOL_CHUNKS);
    int ce = s + (int)(((long long)len * (c + 1)) / POOL_CHUNKS);
    for (int i = cs; i < ce; ++i) m = fmaxf(m, h2f(H[(size_t)i * LDH + t]));
  }
  part[(size_t)(g * POOL_CHUNKS + c) * DOUT + t] = m;
}

__global__ void k_pool2(const float* __restrict__ part, float* __restrict__ pooled) {
  int g = blockIdx.x, t = threadIdx.x;
  if (t >= DOUT) return;
  float m = -3.4e38f;
  #pragma unroll
  for (int c = 0; c < POOL_CHUNKS; ++c)
    m = fmaxf(m, part[(size_t)(g * POOL_CHUNKS + c) * DOUT + t]);
  pooled[(size_t)g * DOUT + t] = m;
}

__global__ void k_cls(const float* __restrict__ pooled, const float* __restrict__ Wcls,
                      const float* __restrict__ bcls, float* __restrict__ out) {
  int g = threadIdx.x;
  if (g >= N_GRAPHS) return;
  float l0 = bcls[0], l1 = bcls[1];
  for (int d = 0; d < DOUT; ++d) {
    float p = pooled[(size_t)g * DOUT + d];
    l0 += p * Wcls[d * 2 + 0];
    l1 += p * Wcls[d * 2 + 1];
  }
  float m = fmaxf(l0, l1);
  float e0 = expf(l0 - m), e1 = expf(l1 - m);
  float inv = 1.0f / (e0 + e1);
  out[g * 2 + 0] = e0 * inv;
  out[g * 2 + 1] = e1 * inv;
}

static inline size_t align256(size_t x) { return (x + 255) & ~(size_t)255; }

extern "C" void kernel_launch(void* const* d_in, const int* in_sizes, int n_in,
                              void* d_out, int out_size, void* d_ws, size_t ws_size,
                              hipStream_t stream) {
  const float* x     = (const float*)d_in[0];
  const int*   ei    = (const int*)d_in[1];
  const int*   batch = (const int*)d_in[2];
  const float* W1    = (const float*)d_in[3];
  const float* b1    = (const float*)d_in[4];
  const float* Wc    = (const float*)d_in[5];
  const float* bc    = (const float*)d_in[6];
  const float* W2    = (const float*)d_in[7];
  const float* b2    = (const float*)d_in[8];
  const float* W3    = (const float*)d_in[9];
  const float* b3    = (const float*)d_in[10];
  const float* Wcls  = (const float*)d_in[11];
  const float* bcls  = (const float*)d_in[12];
  float* out = (float*)d_out;

  const int N = N_NODES, E = N_EDGES;
  const int* src = ei;
  const int* dst = ei + E;

  char* ws = (char*)d_ws;
  size_t off = 0;
  float* dinv   = (float*)(ws + off); off = align256(off + (size_t)N * 4);
  int*   rowptr = (int*)  (ws + off); off = align256(off + (size_t)(N + 1) * 4);
  int*   col    = (int*)  (ws + off); off = align256(off + (size_t)E * 4);
  uint2* colw   = (uint2*)(ws + off); off = align256(off + (size_t)E * 8);
  int*   gcur   = (int*)  (ws + off); off = align256(off + (size_t)NB * 4);
  int*   boffs  = (int*)  (ws + off); off = align256(off + (size_t)(NB + 1) * 4);
  int*   gstart = (int*)  (ws + off); off = align256(off + 512);
  int*   gend   = (int*)  (ws + off); off = align256(off + 512);
  float* pooled = (float*)(ws + off); off = align256(off + (size_t)N_GRAPHS * DOUT * 4);
  float* Wc2    = (float*)(ws + off); off = align256(off + (size_t)DOUT * DOUT * 4);
  float* bc2    = (float*)(ws + off); off = align256(off + (size_t)DOUT * 4);
  u16*   Wpk1   = (u16*)  (ws + off); off = align256(off + (size_t)4 * 13 * 64 * 8 * 2);
  u16*   Wpk2   = (u16*)  (ws + off); off = align256(off + (size_t)7 * 13 * 64 * 8 * 2);
  u16*   Wpk3   = (u16*)  (ws + off); off = align256(off + (size_t)7 * 13 * 64 * 8 * 2);
  u16*   buf0   = (u16*)  (ws + off); off = align256(off + (size_t)N * LDH * 2);
  u16*   buf1   = (u16*)  (ws + off); off = align256(off + (size_t)N * LDH * 2);
  u16*   buf2   = (u16*)  (ws + off); off = align256(off + (size_t)N * LDH * 2);

  uint2* ebuf = (uint2*)buf1;    // 14.5 MB bucket scratch aliases buf1 (dead until GEMM1)
  u16*   xh   = buf2;            // 25.6 MB f16 input aliases buf2 (dead until GEMM2 output)
  float* part = (float*)buf0;    // pooling partials alias buf0 (dead at pool time)

  int nb = (N + 255) / 256;
  int eb = (E + 255) / 256;

  // ---- CSR + degree via bucketed two-phase build (no fine-grained global atomics) ----
  k_init0<<<1, 128, 0, stream>>>(gcur, gstart, gend);
  k_bucket<<<(E + EPB - 1) / EPB, 256, 0, stream>>>(src, dst, gcur, ebuf, E);
  k_bscan<<<1, 64, 0, stream>>>(gcur, boffs, rowptr);
  k_csr<<<NB, 256, 0, stream>>>(ebuf, gcur, boffs, rowptr, dinv, col);
  k_fusew<<<eb, 256, 0, stream>>>(col, dinv, colw, E);
  k_gbound<<<nb, 256, 0, stream>>>(batch, gstart, gend, N);
  // f16 input conversion (tight LDX=128 layout, halves layer-1 gather bytes)
  k_x2h<<<(N * 64 + 255) / 256, 256, 0, stream>>>(x, xh);

  // ---- weight fold + f16 fragment pre-pack ----
  k_comb<<<(201 * DOUT + 255) / 256, 256, 0, stream>>>(Wc, bc, W2, Wc2, bc2);
  k_pack<<<(4 * 13 * 64 + 255) / 256, 256, 0, stream>>>(W1,  DIN,  4 * 13 * 64, Wpk1);
  k_pack<<<(7 * 13 * 64 + 255) / 256, 256, 0, stream>>>(Wc2, DOUT, 7 * 13 * 64, Wpk2);
  k_pack<<<(7 * 13 * 64 + 255) / 256, 256, 0, stream>>>(W3,  DOUT, 7 * 13 * 64, Wpk3);

  int gemmb = (N + 63) / 64;
  int aggb  = (N + 3) / 4;

  // layer 1: aggregate xh (f16, LDX) then MFMA GEMM W1 (+b1, relu)
  k_agg100h<<<aggb, 256, 0, stream>>>(xh, dinv, rowptr, colw, buf0);
  k_gemm_mfma<4><<<gemmb, 256, 0, stream>>>(buf0, LDX, Wpk1, b1, buf1, 1, N);
  // folded middle linear + conv2 pre-mix: T2 = H1 @ (Wc@W2) + bc@W2  (xh dead; buf2 ok)
  k_gemm_mfma<7><<<gemmb, 256, 0, stream>>>(buf1, LDH, Wpk2, bc2, buf2, 0, N);
  // conv2 aggregate + b2 + relu
  k_agg200h<<<aggb, 256, 0, stream>>>(buf2, dinv, rowptr, colw, b2, buf0, 1);
  // conv3: T3 = H2 @ W3 ; H3 = agg(T3) + b3
  k_gemm_mfma<7><<<gemmb, 256, 0, stream>>>(buf0, LDH, Wpk3, nullptr, buf1, 0, N);
  k_agg200h<<<aggb, 256, 0, stream>>>(buf1, dinv, rowptr, colw, b3, buf2, 0);

  // pool (chunked) + classifier
  dim3 pg(N_GRAPHS, POOL_CHUNKS);
  k_pool1h<<<pg, 256, 0, stream>>>(buf2, gstart, gend, part);
  k_pool2<<<N_GRAPHS, 256, 0, stream>>>(part, pooled);
  k_cls<<<1, 128, 0, stream>>>(pooled, Wcls, bcls, out);
}